// Round 12
// baseline (2648.201 us; speedup 1.0000x reference)
//
#include <hip/hip_runtime.h>
#include <stdint.h>

// ---------------- problem dims ----------------
#define BB   64
#define TT   256
#define CIN  512
#define HH   1024
#define NBLK 192     // 64 L0 blocks (16 units) + 128 L1 blocks (8 units)
#define NTHR 256

// ---------------- workspace layout (bytes) ----------------
#define OFF_WP0 0ull                 // 64*4*48*64*16 = 12 MB   [bw][wave][j48][lane][16B]
#define OFF_WP1 12582912ull          // 128*4*32*64*16 = 16 MB  [bw][wave][j32][lane][16B]
#define OFF_XP  29360128ull          // [t256][F64][lane][16B] = 16 MB
#define OFF_B0S 46137344ull          // 4096 f32 (bih0+bhh0)
#define OFF_B1S 46153728ull          // 4096 f32
#define OFF_H0  46170112ull          // 4 x 128 KB ring
#define OFF_H1  46694400ull          // 4 x 128 KB ring
#define OFF_FLG 47218688ull          // 192 u32 flags (0..63 = L0, 64..191 = L1)
#define SZ_HP   131072ull
#define ZERO_SZ (8*SZ_HP + 1024)

typedef short bf16x8 __attribute__((ext_vector_type(8)));
typedef float f32x4 __attribute__((ext_vector_type(4)));
typedef int   i32x4 __attribute__((ext_vector_type(4)));

__device__ i32x4 llvm_amdgcn_raw_buffer_load_i32x4(i32x4 srsrc, int voffset, int soffset,
                                                   int cachepolicy) __asm("llvm.amdgcn.raw.buffer.load.v4i32");
__device__ void  llvm_amdgcn_raw_buffer_store_i32x4(i32x4 vdata, i32x4 srsrc, int voffset,
                                                    int soffset, int cachepolicy) __asm("llvm.amdgcn.raw.buffer.store.v4i32");
#define CP_SC01 17   // sc0|sc1: device-coherent, L1/L2-bypass (R11-proven)

static __device__ __forceinline__ i32x4 make_srd(const char* p) {
  i32x4 r;
  r.x = (int)(uint32_t)(uintptr_t)p;
  r.y = (int)(uint32_t)((uintptr_t)p >> 32);
  r.z = (int)0xFFFFFFFF;
  r.w = 0x00020000;
  return r;
}
static __device__ __forceinline__ uint4 bload(i32x4 srd, int voff) {
  return __builtin_bit_cast(uint4, llvm_amdgcn_raw_buffer_load_i32x4(srd, voff, 0, CP_SC01));
}
static __device__ __forceinline__ void bstore(i32x4 srd, int voff, uint4 v) {
  llvm_amdgcn_raw_buffer_store_i32x4(__builtin_bit_cast(i32x4, v), srd, voff, 0, CP_SC01);
}

static __device__ __forceinline__ uint16_t f2b(float f) {
  union { float f; uint32_t u; } v; v.f = f;
  uint32_t r = (v.u + 0x7FFFu + ((v.u >> 16) & 1u)) >> 16;  // RNE
  return (uint16_t)r;
}
static __device__ __forceinline__ uint4 cvt8(const float* s) {
  uint4 o;
  o.x = (uint32_t)f2b(s[0]) | ((uint32_t)f2b(s[1]) << 16);
  o.y = (uint32_t)f2b(s[2]) | ((uint32_t)f2b(s[3]) << 16);
  o.z = (uint32_t)f2b(s[4]) | ((uint32_t)f2b(s[5]) << 16);
  o.w = (uint32_t)f2b(s[6]) | ((uint32_t)f2b(s[7]) << 16);
  return o;
}
static __device__ __forceinline__ f32x4 mfma16(uint4 a, uint4 b, f32x4 c) {
  return __builtin_amdgcn_mfma_f32_16x16x32_bf16(
      __builtin_bit_cast(bf16x8, a), __builtin_bit_cast(bf16x8, b), c, 0, 0, 0);
}
static __device__ __forceinline__ float sigm(float x)  { return 1.0f / (1.0f + __expf(-x)); }
static __device__ __forceinline__ float tanhx(float x) { return 1.0f - 2.0f / (__expf(2.0f * x) + 1.0f); }
static __device__ __forceinline__ int imin2(int a, int b) { return a < b ? a : b; }

#define FLD(i) ((int)__hip_atomic_load(fl + (i), __ATOMIC_RELAXED, __HIP_MEMORY_SCOPE_AGENT))

// ---------------- pack kernels (identical to R4-R11) ----------------
__global__ void pack_w0(const float* __restrict__ wih, const float* __restrict__ whh,
                        char* __restrict__ ws) {
  uint32_t u = blockIdx.x * blockDim.x + threadIdx.x;   // 786432
  int lane = u & 63;
  uint32_t idx = u >> 6;            // (bw*4 + w)*48 + j
  int j = (int)(idx % 48u);
  uint32_t r2 = idx / 48u;
  int w = r2 & 3, bw = r2 >> 2;
  int c = (j & 3) * 16 + (lane & 15);
  int g_row = (c & 3) * 1024 + bw * 16 + (c >> 2);
  uint4 v;
  if (j < 16) {
    int k = w * 128 + (j >> 2) * 32 + (lane >> 4) * 8;
    v = cvt8(wih + (size_t)g_row * 512 + k);
  } else {
    int k = w * 256 + ((j - 16) >> 2) * 32 + (lane >> 4) * 8;
    v = cvt8(whh + (size_t)g_row * 1024 + k);
  }
  ((uint4*)(ws + OFF_WP0))[u] = v;
}
__global__ void pack_w1(const float* __restrict__ wih, const float* __restrict__ whh,
                        char* __restrict__ ws) {
  uint32_t u = blockIdx.x * blockDim.x + threadIdx.x;   // 1048576
  int lane = u & 63;
  int j = (u >> 6) & 31;
  int w = (u >> 11) & 3;
  int bw = u >> 13;
  int c = (j & 1) * 16 + (lane & 15);
  int g_row = (c & 3) * 1024 + bw * 8 + (c >> 2);
  int k = w * 512 + (j >> 1) * 32 + (lane >> 4) * 8;
  uint4 v;
  if (k < 1024) v = cvt8(wih + (size_t)g_row * 1024 + k);
  else          v = cvt8(whh + (size_t)g_row * 1024 + (k - 1024));
  ((uint4*)(ws + OFF_WP1))[u] = v;
}
__global__ void pack_x(const float* __restrict__ x, char* __restrict__ ws) {
  uint32_t u = blockIdx.x * blockDim.x + threadIdx.x;   // 1048576
  int lane = u & 63;
  int F = (u >> 6) & 63;
  int t = u >> 12;
  int r = (F & 3) * 16 + (lane & 15);
  int k = (F >> 2) * 32 + (lane >> 4) * 8;
  ((uint4*)(ws + OFF_XP))[u] = cvt8(x + (size_t)r * (TT * CIN) + (size_t)t * CIN + k);
}
__global__ void pack_bias(const float* __restrict__ bih0, const float* __restrict__ bhh0,
                          const float* __restrict__ bih1, const float* __restrict__ bhh1,
                          char* __restrict__ ws) {
  uint32_t v = blockIdx.x * blockDim.x + threadIdx.x;   // 8192
  if (v < 4096) ((float*)(ws + OFF_B0S))[v] = bih0[v] + bhh0[v];
  else          ((float*)(ws + OFF_B1S))[v - 4096] = bih1[v - 4096] + bhh1[v - 4096];
}

// ---------------- per-slice waits (tight RAW on own producers, loose global WAR) ----------------
// flags[blk] = completed phases. Writer of slot q&3 at end of phase q overwrites data
// last read at phase q-3 -> WAR safe if global flags >= q-2 (checked loose, slack 2).
static __device__ __forceinline__ void wait_L0w(uint32_t* fl, int tgt, int wave) {
  const int lane = threadIdx.x & 63;
  const int si = 16 * wave + (lane & 15);       // my 16 h0 producers
  for (;;) {
    int fs = FLD(si);
    int f0 = FLD(lane);
    int f1 = FLD(64 + lane);
    int f2 = FLD(128 + lane);
    int mn = imin2(f0, imin2(f1, f2));
    if (__all(fs >= tgt && mn >= tgt - 2)) break;
    __builtin_amdgcn_s_sleep(1);
  }
  __builtin_amdgcn_fence(__ATOMIC_ACQUIRE, "workgroup");
}
static __device__ __forceinline__ void wait_L1a(uint32_t* fl, int tgt, int wave) {
  const int lane = threadIdx.x & 63;
  const int si = 32 * wave + (lane & 31);       // my 32 h0 producers (wave 0 or 1)
  for (;;) {
    int fs = FLD(si);
    int f1 = FLD(64 + lane);
    int f2 = FLD(128 + lane);
    int mn = imin2(f1, f2);
    if (__all(fs >= tgt && mn >= tgt - 2)) break;
    __builtin_amdgcn_s_sleep(1);
  }
  __builtin_amdgcn_fence(__ATOMIC_ACQUIRE, "workgroup");
}
static __device__ __forceinline__ void wait_L1b(uint32_t* fl, int tgt, int wave) {
  const int lane = threadIdx.x & 63;
  const int tb = (wave == 2) ? 64 : 128;        // my 64 h1 producers
  const int ob = (wave == 2) ? 128 : 64;        // other L1 half (loose)
  for (;;) {
    int fs = FLD(tb + lane);
    int fo = FLD(ob + lane);
    if (__all(fs >= tgt && fo >= tgt - 2)) break;
    __builtin_amdgcn_s_sleep(1);
  }
  __builtin_amdgcn_fence(__ATOMIC_ACQUIRE, "workgroup");
}

// ---------------- persistent LSTM ----------------
// blocks 0..63: layer0, 16 units each; blocks 64..191: layer1, 8 units each.
// phase p: L0 computes t=p (p<256), L1 computes t=p-1 (p>=1).
// h rings: write slot p&3, read slot (p+3)&3. Transport: buffer dwordx4 sc0 sc1.
__global__ __launch_bounds__(NTHR, 1) void lstm_persist(char* __restrict__ ws,
                                                        float* __restrict__ out) {
  __shared__ float cpart[16384];                 // 64 KB partial-sum exchange
  __shared__ __align__(16) uint16_t hreg[1024];  // 2 KB staged h tile
  const int tid = threadIdx.x, blk = blockIdx.x;
  const int wave = tid >> 6, lane = tid & 63;
  const bool isL1 = blk >= 64;
  const int bw = isL1 ? blk - 64 : blk;
  uint32_t* flags = (uint32_t*)(ws + OFF_FLG);

  const int eu  = isL1 ? (tid & 7)  : (tid & 15);
  const int erb = isL1 ? (tid >> 3) : (tid >> 4);
  const int ug  = isL1 ? (bw * 8 + eu) : (bw * 16 + eu);
  const float* bsrc = (const float*)(ws + (isL1 ? OFF_B1S : OFF_B0S));
  const float bs0 = bsrc[ug], bs1 = bsrc[1024 + ug], bs2 = bsrc[2048 + ug], bs3 = bsrc[3072 + ug];
  float cst[4] = {0.f, 0.f, 0.f, 0.f};

  // ---- persistent register-resident weights (h-part only for L0; x-B streamed) ----
  uint4 b[32];
  const uint4* bxs = nullptr;   // L0 x-part B, streamed from L2 each phase
  if (isL1) {
    const uint4* bp = (const uint4*)(ws + OFF_WP1) + ((size_t)(bw * 4 + wave) * 32) * 64 + lane;
    #pragma unroll
    for (int j = 0; j < 32; ++j) b[j] = bp[(size_t)j * 64];
  } else {
    const uint4* bp = (const uint4*)(ws + OFF_WP0) + ((size_t)(bw * 4 + wave) * 48) * 64 + lane;
    bxs = bp;                                   // j = 0..15 (x-part), read per phase
    #pragma unroll
    for (int j = 0; j < 32; ++j) b[j] = bp[(size_t)(16 + j) * 64];   // h-part
  }

  for (int p = 0; p <= 256; ++p) {
    f32x4 acc[4][4];
    #pragma unroll
    for (int rf = 0; rf < 4; ++rf)
      #pragma unroll
      for (int cf = 0; cf < 4; ++cf)
        acc[rf][cf] = (f32x4){0.f, 0.f, 0.f, 0.f};

    if (!isL1) {
      if (p == 256) break;
      // x-part first (plain cached loads incl. streamed B): before the wait
      const uint4* xpl = (const uint4*)(ws + OFF_XP) + (size_t)p * 4096 + lane;
      #pragma unroll
      for (int jx = 0; jx < 4; ++jx) {
        const int kf = wave * 4 + jx;
        uint4 a0 = xpl[kf * 256], a1 = xpl[kf * 256 + 64],
              a2 = xpl[kf * 256 + 128], a3 = xpl[kf * 256 + 192];
        #pragma unroll
        for (int cf = 0; cf < 4; ++cf) {
          uint4 bb = bxs[(size_t)(jx * 4 + cf) * 64];
          acc[0][cf] = mfma16(a0, bb, acc[0][cf]);
          acc[1][cf] = mfma16(a1, bb, acc[1][cf]);
          acc[2][cf] = mfma16(a2, bb, acc[2][cf]);
          acc[3][cf] = mfma16(a3, bb, acc[3][cf]);
        }
      }
      if (p > 0) wait_L0w(flags, p, wave);
      const i32x4 srdh = make_srd(ws + OFF_H0 + (size_t)((p + 3) & 3) * SZ_HP);
      #pragma unroll
      for (int jh = 0; jh < 8; ++jh) {
        const int kf = wave * 8 + jh;
        const int base = (kf * 256 + lane) * 16;
        uint4 a0 = bload(srdh, base);
        uint4 a1 = bload(srdh, base + 64 * 16);
        uint4 a2 = bload(srdh, base + 128 * 16);
        uint4 a3 = bload(srdh, base + 192 * 16);
        #pragma unroll
        for (int cf = 0; cf < 4; ++cf) {
          uint4 bb = b[jh * 4 + cf];
          acc[0][cf] = mfma16(a0, bb, acc[0][cf]);
          acc[1][cf] = mfma16(a1, bb, acc[1][cf]);
          acc[2][cf] = mfma16(a2, bb, acc[2][cf]);
          acc[3][cf] = mfma16(a3, bb, acc[3][cf]);
        }
      }
    } else {
      if (p == 0) {
        if (tid == 0)
          __hip_atomic_store(flags + blk, 1u, __ATOMIC_RELAXED, __HIP_MEMORY_SCOPE_AGENT);
        continue;
      }
      if (wave < 2) wait_L1a(flags, p, wave);
      else          wait_L1b(flags, p, wave);
      uint32_t boff = (uint32_t)(wave < 2 ? OFF_H0 : OFF_H1) + ((p + 3) & 3) * (uint32_t)SZ_HP;
      boff = __builtin_amdgcn_readfirstlane(boff);
      const i32x4 srdh = make_srd(ws + boff);
      const int kb = (wave & 1) * 16;
      #pragma unroll
      for (int jh = 0; jh < 16; ++jh) {
        const int kf = kb + jh;
        const int base = (kf * 256 + lane) * 16;
        uint4 a0 = bload(srdh, base);
        uint4 a1 = bload(srdh, base + 64 * 16);
        uint4 a2 = bload(srdh, base + 128 * 16);
        uint4 a3 = bload(srdh, base + 192 * 16);
        #pragma unroll
        for (int cf = 0; cf < 2; ++cf) {
          uint4 bb = b[jh * 2 + cf];
          acc[0][cf] = mfma16(a0, bb, acc[0][cf]);
          acc[1][cf] = mfma16(a1, bb, acc[1][cf]);
          acc[2][cf] = mfma16(a2, bb, acc[2][cf]);
          acc[3][cf] = mfma16(a3, bb, acc[3][cf]);
        }
      }
    }

    // ---- stash K-quarter partials ----
    if (isL1) {
      #pragma unroll
      for (int rf = 0; rf < 4; ++rf)
        #pragma unroll
        for (int cf = 0; cf < 2; ++cf)
          *(f32x4*)&cpart[(((wave * 4 + rf) * 2 + cf) * 64 + lane) * 4] = acc[rf][cf];
    } else {
      #pragma unroll
      for (int rf = 0; rf < 4; ++rf)
        #pragma unroll
        for (int cf = 0; cf < 4; ++cf)
          *(f32x4*)&cpart[(((wave * 4 + rf) * 4 + cf) * 64 + lane) * 4] = acc[rf][cf];
    }
    __syncthreads();

    // ---- reduce + elementwise (c-state in f32 registers) ----
    if (isL1) {
      #pragma unroll
      for (int half = 0; half < 2; ++half) {
        const int r64 = erb + half * 32;
        const int rf = r64 >> 4, r16 = r64 & 15;
        const int reg = r16 & 3, lbase = 16 * (r16 >> 2);
        float gs[4];
        #pragma unroll
        for (int g = 0; g < 4; ++g) {
          const int c = eu * 4 + g;
          const int lc = (c & 15) + lbase;
          const int cf = c >> 4;
          float s = 0.f;
          #pragma unroll
          for (int w = 0; w < 4; ++w)
            s += cpart[(((w * 4 + rf) * 2 + cf) * 64 + lc) * 4 + reg];
          gs[g] = s;
        }
        const float iv = sigm(gs[0] + bs0), fv = sigm(gs[1] + bs1);
        const float gv = tanhx(gs[2] + bs2), ov = sigm(gs[3] + bs3);
        float cs = cst[half];
        cs = fv * cs + iv * gv;
        cst[half] = cs;
        const float hv = ov * tanhx(cs);
        hreg[r64 * 8 + eu] = f2b(hv);
        if (p == 256) out[(size_t)r64 * 1024 + ug] = hv;
      }
    } else {
      #pragma unroll
      for (int half = 0; half < 4; ++half) {
        const int r64 = erb + half * 16;
        const int rf = half, r16 = erb;
        const int reg = r16 & 3, lbase = 16 * (r16 >> 2);
        float gs[4];
        #pragma unroll
        for (int g = 0; g < 4; ++g) {
          const int c = eu * 4 + g;
          const int lc = (c & 15) + lbase;
          const int cf = c >> 4;
          float s = 0.f;
          #pragma unroll
          for (int w = 0; w < 4; ++w)
            s += cpart[(((w * 4 + rf) * 4 + cf) * 64 + lc) * 4 + reg];
          gs[g] = s;
        }
        const float iv = sigm(gs[0] + bs0), fv = sigm(gs[1] + bs1);
        const float gv = tanhx(gs[2] + bs2), ov = sigm(gs[3] + bs3);
        float cs = cst[half];
        cs = fv * cs + iv * gv;
        cst[half] = cs;
        const float hv = ov * tanhx(cs);
        hreg[r64 * 16 + eu] = f2b(hv);
      }
    }
    __syncthreads();

    // ---- publish: wave0 stores h + drains own vmcnt + flags; waves 1-3 go poll next phase ----
    if (p < 256 && wave == 0) {
      if (isL1) {
        uint4 v = ((const uint4*)hreg)[lane];          // row=lane, units bw*8..+7
        const i32x4 srdw = make_srd(ws + OFF_H1 + (size_t)(p & 3) * SZ_HP);
        const int off = ((bw >> 2) * 4 + (lane >> 4)) * 1024 + (bw & 3) * 256 + (lane & 15) * 16;
        bstore(srdw, off, v);
      } else {
        const i32x4 srdw = make_srd(ws + OFF_H0 + (size_t)(p & 3) * SZ_HP);
        #pragma unroll
        for (int h = 0; h < 2; ++h) {
          const int t = lane + 64 * h;                 // covers 0..127
          uint4 v = ((const uint4*)hreg)[t];           // row t>>1, units (t&1)*8..+8
          const int off = ((bw >> 1) * 4 + (t >> 5)) * 1024
                        + (2 * (bw & 1) + (t & 1)) * 256 + ((t >> 1) & 15) * 16;
          bstore(srdw, off, v);
        }
      }
      asm volatile("s_waitcnt vmcnt(0)" ::: "memory");   // this wave's h stores at coherence point
      if (lane == 0)
        __hip_atomic_store(flags + blk, (uint32_t)(p + 1), __ATOMIC_RELAXED, __HIP_MEMORY_SCOPE_AGENT);
    }
  }
}

// ---------------- launcher ----------------
extern "C" void kernel_launch(void* const* d_in, const int* in_sizes, int n_in,
                              void* d_out, int out_size, void* d_ws, size_t ws_size,
                              hipStream_t stream) {
  const float* x    = (const float*)d_in[0];
  const float* Wih0 = (const float*)d_in[1];
  const float* Whh0 = (const float*)d_in[2];
  const float* bih0 = (const float*)d_in[3];
  const float* bhh0 = (const float*)d_in[4];
  const float* Wih1 = (const float*)d_in[5];
  const float* Whh1 = (const float*)d_in[6];
  const float* bih1 = (const float*)d_in[7];
  const float* bhh1 = (const float*)d_in[8];
  char* ws = (char*)d_ws;
  float* out = (float*)d_out;

  // zero h rings + flags (re-runs on every graph replay)
  hipMemsetAsync(ws + OFF_H0, 0, ZERO_SZ, stream);

  pack_w0  <<<3072, 256, 0, stream>>>(Wih0, Whh0, ws);
  pack_w1  <<<4096, 256, 0, stream>>>(Wih1, Whh1, ws);
  pack_x   <<<4096, 256, 0, stream>>>(x, ws);
  pack_bias<<<32,   256, 0, stream>>>(bih0, bhh0, bih1, bhh1, ws);

  void* args[] = {(void*)&ws, (void*)&out};
  hipError_t e = hipLaunchCooperativeKernel((const void*)lstm_persist, dim3(NBLK),
                                            dim3(NTHR), args, 0, stream);
  if (e != hipSuccess) {
    (void)hipGetLastError();   // clear sticky error; fall back to plain launch
    lstm_persist<<<dim3(NBLK), dim3(NTHR), 0, stream>>>(ws, out);
  }
}

// Round 13
// 2285.722 us; speedup vs baseline: 1.1586x; 1.1586x over previous
//
#include <hip/hip_runtime.h>
#include <stdint.h>

// ---------------- problem dims ----------------
#define BB   64
#define TT   256
#define CIN  512
#define HH   1024
#define NBLK 192     // 64 L0 blocks (16 units) + 128 L1 blocks (8 units)
#define NTHR 256

// ---------------- workspace layout (bytes) ----------------
#define OFF_WP0 0ull                 // 64*4*48*64*16 = 12 MB   [bw][wave][j48][lane][16B]
#define OFF_WP1 12582912ull          // 128*4*32*64*16 = 16 MB  [bw][wave][j32][lane][16B]
#define OFF_XP  29360128ull          // [t256][F64][lane][16B] = 16 MB
#define OFF_B0S 46137344ull          // 4096 f32 (bih0+bhh0)
#define OFF_B1S 46153728ull          // 4096 f32
#define OFF_H0  46170112ull          // 4 x 128 KB ring
#define OFF_H1  46694400ull          // 4 x 128 KB ring
#define OFF_FLG 47218688ull          // 192 u32 flags (0..63 = L0, 64..191 = L1)
#define SZ_HP   131072ull
#define ZERO_SZ (8*SZ_HP + 1024)

typedef short bf16x8 __attribute__((ext_vector_type(8)));
typedef float f32x4 __attribute__((ext_vector_type(4)));
typedef int   i32x4 __attribute__((ext_vector_type(4)));

__device__ i32x4 llvm_amdgcn_raw_buffer_load_i32x4(i32x4 srsrc, int voffset, int soffset,
                                                   int cachepolicy) __asm("llvm.amdgcn.raw.buffer.load.v4i32");
__device__ void  llvm_amdgcn_raw_buffer_store_i32x4(i32x4 vdata, i32x4 srsrc, int voffset,
                                                    int soffset, int cachepolicy) __asm("llvm.amdgcn.raw.buffer.store.v4i32");
#define CP_SC01 17   // sc0|sc1: device-coherent, L1/L2-bypass (R11-proven)

static __device__ __forceinline__ i32x4 make_srd(const char* p) {
  i32x4 r;
  r.x = (int)(uint32_t)(uintptr_t)p;
  r.y = (int)(uint32_t)((uintptr_t)p >> 32);
  r.z = (int)0xFFFFFFFF;
  r.w = 0x00020000;
  return r;
}
static __device__ __forceinline__ uint4 bload(i32x4 srd, int voff) {
  return __builtin_bit_cast(uint4, llvm_amdgcn_raw_buffer_load_i32x4(srd, voff, 0, CP_SC01));
}
static __device__ __forceinline__ void bstore(i32x4 srd, int voff, uint4 v) {
  llvm_amdgcn_raw_buffer_store_i32x4(__builtin_bit_cast(i32x4, v), srd, voff, 0, CP_SC01);
}

static __device__ __forceinline__ uint16_t f2b(float f) {
  union { float f; uint32_t u; } v; v.f = f;
  uint32_t r = (v.u + 0x7FFFu + ((v.u >> 16) & 1u)) >> 16;  // RNE
  return (uint16_t)r;
}
static __device__ __forceinline__ uint4 cvt8(const float* s) {
  uint4 o;
  o.x = (uint32_t)f2b(s[0]) | ((uint32_t)f2b(s[1]) << 16);
  o.y = (uint32_t)f2b(s[2]) | ((uint32_t)f2b(s[3]) << 16);
  o.z = (uint32_t)f2b(s[4]) | ((uint32_t)f2b(s[5]) << 16);
  o.w = (uint32_t)f2b(s[6]) | ((uint32_t)f2b(s[7]) << 16);
  return o;
}
static __device__ __forceinline__ f32x4 mfma16(uint4 a, uint4 b, f32x4 c) {
  return __builtin_amdgcn_mfma_f32_16x16x32_bf16(
      __builtin_bit_cast(bf16x8, a), __builtin_bit_cast(bf16x8, b), c, 0, 0, 0);
}
static __device__ __forceinline__ float sigm(float x)  { return 1.0f / (1.0f + __expf(-x)); }
static __device__ __forceinline__ float tanhx(float x) { return 1.0f - 2.0f / (__expf(2.0f * x) + 1.0f); }
static __device__ __forceinline__ int imin2(int a, int b) { return a < b ? a : b; }

#define FLD(i) ((int)__hip_atomic_load(fl + (i), __ATOMIC_RELAXED, __HIP_MEMORY_SCOPE_AGENT))
#define CROW 65   // padded cpart row stride in uint4 units (bank-conflict fix)

// ---------------- pack kernels (identical to R4-R11) ----------------
__global__ void pack_w0(const float* __restrict__ wih, const float* __restrict__ whh,
                        char* __restrict__ ws) {
  uint32_t u = blockIdx.x * blockDim.x + threadIdx.x;   // 786432
  int lane = u & 63;
  uint32_t idx = u >> 6;            // (bw*4 + w)*48 + j
  int j = (int)(idx % 48u);
  uint32_t r2 = idx / 48u;
  int w = r2 & 3, bw = r2 >> 2;
  int c = (j & 3) * 16 + (lane & 15);
  int g_row = (c & 3) * 1024 + bw * 16 + (c >> 2);
  uint4 v;
  if (j < 16) {
    int k = w * 128 + (j >> 2) * 32 + (lane >> 4) * 8;
    v = cvt8(wih + (size_t)g_row * 512 + k);
  } else {
    int k = w * 256 + ((j - 16) >> 2) * 32 + (lane >> 4) * 8;
    v = cvt8(whh + (size_t)g_row * 1024 + k);
  }
  ((uint4*)(ws + OFF_WP0))[u] = v;
}
__global__ void pack_w1(const float* __restrict__ wih, const float* __restrict__ whh,
                        char* __restrict__ ws) {
  uint32_t u = blockIdx.x * blockDim.x + threadIdx.x;   // 1048576
  int lane = u & 63;
  int j = (u >> 6) & 31;
  int w = (u >> 11) & 3;
  int bw = u >> 13;
  int c = (j & 1) * 16 + (lane & 15);
  int g_row = (c & 3) * 1024 + bw * 8 + (c >> 2);
  int k = w * 512 + (j >> 1) * 32 + (lane >> 4) * 8;
  uint4 v;
  if (k < 1024) v = cvt8(wih + (size_t)g_row * 1024 + k);
  else          v = cvt8(whh + (size_t)g_row * 1024 + (k - 1024));
  ((uint4*)(ws + OFF_WP1))[u] = v;
}
__global__ void pack_x(const float* __restrict__ x, char* __restrict__ ws) {
  uint32_t u = blockIdx.x * blockDim.x + threadIdx.x;   // 1048576
  int lane = u & 63;
  int F = (u >> 6) & 63;
  int t = u >> 12;
  int r = (F & 3) * 16 + (lane & 15);
  int k = (F >> 2) * 32 + (lane >> 4) * 8;
  ((uint4*)(ws + OFF_XP))[u] = cvt8(x + (size_t)r * (TT * CIN) + (size_t)t * CIN + k);
}
__global__ void pack_bias(const float* __restrict__ bih0, const float* __restrict__ bhh0,
                          const float* __restrict__ bih1, const float* __restrict__ bhh1,
                          char* __restrict__ ws) {
  uint32_t v = blockIdx.x * blockDim.x + threadIdx.x;   // 8192
  if (v < 4096) ((float*)(ws + OFF_B0S))[v] = bih0[v] + bhh0[v];
  else          ((float*)(ws + OFF_B1S))[v - 4096] = bih1[v - 4096] + bhh1[v - 4096];
}

// ---------------- group-split waits (R11-proven, byte-identical) ----------------
static __device__ __forceinline__ void wait_L0(uint32_t* fl, int tgt) {
  const int lane = threadIdx.x & 63;
  for (;;) {
    int f0 = FLD(lane);
    int f1 = FLD(64 + lane);
    int f2 = FLD(128 + lane);
    int mn1 = imin2(f1, f2);
    if (__all(f0 >= tgt && mn1 >= tgt - 2)) break;
    __builtin_amdgcn_s_sleep(1);
  }
  __builtin_amdgcn_fence(__ATOMIC_ACQUIRE, "workgroup");
}
static __device__ __forceinline__ void wait_L1a(uint32_t* fl, int tgt) {
  const int lane = threadIdx.x & 63;
  for (;;) {
    int f0 = FLD(lane);
    if (__all(f0 >= tgt)) break;
    __builtin_amdgcn_s_sleep(1);
  }
  __builtin_amdgcn_fence(__ATOMIC_ACQUIRE, "workgroup");
}
static __device__ __forceinline__ void wait_L1b(uint32_t* fl, int tgt) {
  const int lane = threadIdx.x & 63;
  for (;;) {
    int f1 = FLD(64 + lane);
    int f2 = FLD(128 + lane);
    int mn = imin2(f1, f2);
    if (__all(mn >= tgt)) break;
    __builtin_amdgcn_s_sleep(1);
  }
  __builtin_amdgcn_fence(__ATOMIC_ACQUIRE, "workgroup");
}

// ---------------- persistent LSTM ----------------
// blocks 0..63: layer0, 16 units each; blocks 64..191: layer1, 8 units each.
// phase p: L0 computes t=p (p<256), L1 computes t=p-1 (p>=1).
// h rings: write slot p&3, read slot (p+3)&3. Transport: buffer dwordx4 sc0 sc1 (R11).
__global__ __launch_bounds__(NTHR, 1) void lstm_persist(char* __restrict__ ws,
                                                        float* __restrict__ out) {
  __shared__ float cpart[64 * CROW * 4];         // padded: 64 rows x 65 uint4 (~65 KB)
  __shared__ __align__(16) uint16_t hreg[1024];  // 2 KB staged h tile
  const int tid = threadIdx.x, blk = blockIdx.x;
  const int wave = tid >> 6, lane = tid & 63;
  const bool isL1 = blk >= 64;
  const int bw = isL1 ? blk - 64 : blk;
  uint32_t* flags = (uint32_t*)(ws + OFF_FLG);

  const int eu  = isL1 ? (tid & 7)  : (tid & 15);
  const int erb = isL1 ? (tid >> 3) : (tid >> 4);
  const int ug  = isL1 ? (bw * 8 + eu) : (bw * 16 + eu);
  const float* bsrc = (const float*)(ws + (isL1 ? OFF_B1S : OFF_B0S));
  const float bs0 = bsrc[ug], bs1 = bsrc[1024 + ug], bs2 = bsrc[2048 + ug], bs3 = bsrc[3072 + ug];
  float cst[4] = {0.f, 0.f, 0.f, 0.f};

  // ---- persistent register-resident weights: 32 frags (no spill).
  // L0 keeps only the h-part resident; x-part B streams from L2 each phase.
  uint4 b[32];
  const uint4* bxs = nullptr;
  if (isL1) {
    const uint4* bp = (const uint4*)(ws + OFF_WP1) + ((size_t)(bw * 4 + wave) * 32) * 64 + lane;
    #pragma unroll
    for (int j = 0; j < 32; ++j) b[j] = bp[(size_t)j * 64];
  } else {
    const uint4* bp = (const uint4*)(ws + OFF_WP0) + ((size_t)(bw * 4 + wave) * 48) * 64 + lane;
    bxs = bp;                                   // j = 0..15 (x-part), streamed per phase
    #pragma unroll
    for (int j = 0; j < 32; ++j) b[j] = bp[(size_t)(16 + j) * 64];   // h-part resident
  }

  for (int p = 0; p <= 256; ++p) {
    f32x4 acc[4][4];
    #pragma unroll
    for (int rf = 0; rf < 4; ++rf)
      #pragma unroll
      for (int cf = 0; cf < 4; ++cf)
        acc[rf][cf] = (f32x4){0.f, 0.f, 0.f, 0.f};

    if (!isL1) {
      if (p == 256) break;
      // x-part first (plain cached loads incl. streamed B): before the wait
      const uint4* xpl = (const uint4*)(ws + OFF_XP) + (size_t)p * 4096 + lane;
      #pragma unroll
      for (int jx = 0; jx < 4; ++jx) {
        const int kf = wave * 4 + jx;
        uint4 a0 = xpl[kf * 256], a1 = xpl[kf * 256 + 64],
              a2 = xpl[kf * 256 + 128], a3 = xpl[kf * 256 + 192];
        #pragma unroll
        for (int cf = 0; cf < 4; ++cf) {
          uint4 bb = bxs[(size_t)(jx * 4 + cf) * 64];
          acc[0][cf] = mfma16(a0, bb, acc[0][cf]);
          acc[1][cf] = mfma16(a1, bb, acc[1][cf]);
          acc[2][cf] = mfma16(a2, bb, acc[2][cf]);
          acc[3][cf] = mfma16(a3, bb, acc[3][cf]);
        }
      }
      if (p > 0) wait_L0(flags, p);
      const i32x4 srdh = make_srd(ws + OFF_H0 + (size_t)((p + 3) & 3) * SZ_HP);
      #pragma unroll
      for (int jh = 0; jh < 8; ++jh) {
        const int kf = wave * 8 + jh;
        const int base = (kf * 256 + lane) * 16;
        uint4 a0 = bload(srdh, base);
        uint4 a1 = bload(srdh, base + 64 * 16);
        uint4 a2 = bload(srdh, base + 128 * 16);
        uint4 a3 = bload(srdh, base + 192 * 16);
        #pragma unroll
        for (int cf = 0; cf < 4; ++cf) {
          uint4 bb = b[jh * 4 + cf];
          acc[0][cf] = mfma16(a0, bb, acc[0][cf]);
          acc[1][cf] = mfma16(a1, bb, acc[1][cf]);
          acc[2][cf] = mfma16(a2, bb, acc[2][cf]);
          acc[3][cf] = mfma16(a3, bb, acc[3][cf]);
        }
      }
    } else {
      if (p == 0) {
        if (tid == 0)
          __hip_atomic_store(flags + blk, 1u, __ATOMIC_RELAXED, __HIP_MEMORY_SCOPE_AGENT);
        continue;
      }
      if (wave < 2) wait_L1a(flags, p);
      else          wait_L1b(flags, p);
      uint32_t boff = (uint32_t)(wave < 2 ? OFF_H0 : OFF_H1) + ((p + 3) & 3) * (uint32_t)SZ_HP;
      boff = __builtin_amdgcn_readfirstlane(boff);
      const i32x4 srdh = make_srd(ws + boff);
      const int kb = (wave & 1) * 16;
      #pragma unroll
      for (int jh = 0; jh < 16; ++jh) {
        const int kf = kb + jh;
        const int base = (kf * 256 + lane) * 16;
        uint4 a0 = bload(srdh, base);
        uint4 a1 = bload(srdh, base + 64 * 16);
        uint4 a2 = bload(srdh, base + 128 * 16);
        uint4 a3 = bload(srdh, base + 192 * 16);
        #pragma unroll
        for (int cf = 0; cf < 2; ++cf) {
          uint4 bb = b[jh * 2 + cf];
          acc[0][cf] = mfma16(a0, bb, acc[0][cf]);
          acc[1][cf] = mfma16(a1, bb, acc[1][cf]);
          acc[2][cf] = mfma16(a2, bb, acc[2][cf]);
          acc[3][cf] = mfma16(a3, bb, acc[3][cf]);
        }
      }
    }

    // ---- stash K-quarter partials (padded rows: stride CROW uint4) ----
    if (isL1) {
      #pragma unroll
      for (int rf = 0; rf < 4; ++rf)
        #pragma unroll
        for (int cf = 0; cf < 2; ++cf)
          *(f32x4*)&cpart[(((wave * 4 + rf) * 2 + cf) * CROW + lane) * 4] = acc[rf][cf];
    } else {
      #pragma unroll
      for (int rf = 0; rf < 4; ++rf)
        #pragma unroll
        for (int cf = 0; cf < 4; ++cf)
          *(f32x4*)&cpart[(((wave * 4 + rf) * 4 + cf) * CROW + lane) * 4] = acc[rf][cf];
    }
    __syncthreads();

    // ---- reduce + elementwise (c-state in f32 registers) ----
    if (isL1) {
      #pragma unroll
      for (int half = 0; half < 2; ++half) {
        const int r64 = erb + half * 32;
        const int rf = r64 >> 4, r16 = r64 & 15;
        const int reg = r16 & 3, lbase = 16 * (r16 >> 2);
        float gs[4];
        #pragma unroll
        for (int g = 0; g < 4; ++g) {
          const int c = eu * 4 + g;
          const int lc = (c & 15) + lbase;
          const int cf = c >> 4;
          float s = 0.f;
          #pragma unroll
          for (int w = 0; w < 4; ++w)
            s += cpart[(((w * 4 + rf) * 2 + cf) * CROW + lc) * 4 + reg];
          gs[g] = s;
        }
        const float iv = sigm(gs[0] + bs0), fv = sigm(gs[1] + bs1);
        const float gv = tanhx(gs[2] + bs2), ov = sigm(gs[3] + bs3);
        float cs = cst[half];
        cs = fv * cs + iv * gv;
        cst[half] = cs;
        const float hv = ov * tanhx(cs);
        hreg[r64 * 8 + eu] = f2b(hv);
        if (p == 256) out[(size_t)r64 * 1024 + ug] = hv;
      }
    } else {
      #pragma unroll
      for (int half = 0; half < 4; ++half) {
        const int r64 = erb + half * 16;
        const int rf = half, r16 = erb;
        const int reg = r16 & 3, lbase = 16 * (r16 >> 2);
        float gs[4];
        #pragma unroll
        for (int g = 0; g < 4; ++g) {
          const int c = eu * 4 + g;
          const int lc = (c & 15) + lbase;
          const int cf = c >> 4;
          float s = 0.f;
          #pragma unroll
          for (int w = 0; w < 4; ++w)
            s += cpart[(((w * 4 + rf) * 4 + cf) * CROW + lc) * 4 + reg];
          gs[g] = s;
        }
        const float iv = sigm(gs[0] + bs0), fv = sigm(gs[1] + bs1);
        const float gv = tanhx(gs[2] + bs2), ov = sigm(gs[3] + bs3);
        float cs = cst[half];
        cs = fv * cs + iv * gv;
        cst[half] = cs;
        const float hv = ov * tanhx(cs);
        hreg[r64 * 16 + eu] = f2b(hv);
      }
    }
    __syncthreads();

    // ---- publish h: buffer_store_dwordx4 sc0 sc1 -> barrier (drains vmcnt) -> flag (R11) ----
    if (p < 256) {
      if (isL1) {
        if (tid < 64) {
          uint4 v = ((const uint4*)hreg)[tid];          // row tid, units bw*8..+7
          const i32x4 srdw = make_srd(ws + OFF_H1 + (size_t)(p & 3) * SZ_HP);
          const int off = ((bw >> 2) * 4 + (tid >> 4)) * 1024 + (bw & 3) * 256 + (tid & 15) * 16;
          bstore(srdw, off, v);
        }
      } else {
        if (tid < 128) {
          uint4 v = ((const uint4*)hreg)[tid];          // row tid>>1, units (tid&1)*8..+8
          const i32x4 srdw = make_srd(ws + OFF_H0 + (size_t)(p & 3) * SZ_HP);
          const int off = ((bw >> 1) * 4 + (tid >> 5)) * 1024
                        + (2 * (bw & 1) + (tid & 1)) * 256 + ((tid >> 1) & 15) * 16;
          bstore(srdw, off, v);
        }
      }
      __syncthreads();   // each wave's s_waitcnt vmcnt(0) before s_barrier -> stores complete
      if (tid == 0)
        __hip_atomic_store(flags + blk, (uint32_t)(p + 1), __ATOMIC_RELAXED, __HIP_MEMORY_SCOPE_AGENT);
    }
  }
}

// ---------------- launcher ----------------
extern "C" void kernel_launch(void* const* d_in, const int* in_sizes, int n_in,
                              void* d_out, int out_size, void* d_ws, size_t ws_size,
                              hipStream_t stream) {
  const float* x    = (const float*)d_in[0];
  const float* Wih0 = (const float*)d_in[1];
  const float* Whh0 = (const float*)d_in[2];
  const float* bih0 = (const float*)d_in[3];
  const float* bhh0 = (const float*)d_in[4];
  const float* Wih1 = (const float*)d_in[5];
  const float* Whh1 = (const float*)d_in[6];
  const float* bih1 = (const float*)d_in[7];
  const float* bhh1 = (const float*)d_in[8];
  char* ws = (char*)d_ws;
  float* out = (float*)d_out;

  // zero h rings + flags (re-runs on every graph replay)
  hipMemsetAsync(ws + OFF_H0, 0, ZERO_SZ, stream);

  pack_w0  <<<3072, 256, 0, stream>>>(Wih0, Whh0, ws);
  pack_w1  <<<4096, 256, 0, stream>>>(Wih1, Whh1, ws);
  pack_x   <<<4096, 256, 0, stream>>>(x, ws);
  pack_bias<<<32,   256, 0, stream>>>(bih0, bhh0, bih1, bhh1, ws);

  void* args[] = {(void*)&ws, (void*)&out};
  hipError_t e = hipLaunchCooperativeKernel((const void*)lstm_persist, dim3(NBLK),
                                            dim3(NTHR), args, 0, stream);
  if (e != hipSuccess) {
    (void)hipGetLastError();   // clear sticky error; fall back to plain launch
    lstm_persist<<<dim3(NBLK), dim3(NTHR), 0, stream>>>(ws, out);
  }
}

// Round 14
// 1948.718 us; speedup vs baseline: 1.3589x; 1.1729x over previous
//
#include <hip/hip_runtime.h>
#include <stdint.h>

// ---------------- problem dims ----------------
#define BB   64
#define TT   256
#define CIN  512
#define HH   1024
#define NBLK 192     // 64 L0 blocks (16 units) + 128 L1 blocks (8 units)
#define NTHR 256

// ---------------- workspace layout (bytes) ----------------
#define OFF_WP0 0ull                 // 64*4*48*64*16 = 12 MB   [bw][wave][j48][lane][16B]
#define OFF_WP1 12582912ull          // 128*4*32*64*16 = 16 MB  [bw][wave][j32][lane][16B]
#define OFF_XP  29360128ull          // [t256][F64][lane][16B] = 16 MB
#define OFF_B0S 46137344ull          // 4096 f32 (bih0+bhh0)
#define OFF_B1S 46153728ull          // 4096 f32
#define OFF_H0  46170112ull          // 4 x 128 KB ring
#define OFF_H1  46694400ull          // 4 x 128 KB ring
#define OFF_FLG 47218688ull          // 192 u32 flags (0..63 = L0, 64..191 = L1)
#define SZ_HP   131072ull
#define ZERO_SZ (8*SZ_HP + 1024)

typedef short bf16x8 __attribute__((ext_vector_type(8)));
typedef float f32x4 __attribute__((ext_vector_type(4)));
typedef int   i32x4 __attribute__((ext_vector_type(4)));

__device__ i32x4 llvm_amdgcn_raw_buffer_load_i32x4(i32x4 srsrc, int voffset, int soffset,
                                                   int cachepolicy) __asm("llvm.amdgcn.raw.buffer.load.v4i32");
__device__ void  llvm_amdgcn_raw_buffer_store_i32x4(i32x4 vdata, i32x4 srsrc, int voffset,
                                                    int soffset, int cachepolicy) __asm("llvm.amdgcn.raw.buffer.store.v4i32");
#define CP_SC01 17   // sc0|sc1: device-coherent, L1/L2-bypass (R11-proven)

static __device__ __forceinline__ i32x4 make_srd(const char* p) {
  i32x4 r;
  r.x = (int)(uint32_t)(uintptr_t)p;
  r.y = (int)(uint32_t)((uintptr_t)p >> 32);
  r.z = (int)0xFFFFFFFF;
  r.w = 0x00020000;
  return r;
}
static __device__ __forceinline__ uint4 bload(i32x4 srd, int voff) {
  return __builtin_bit_cast(uint4, llvm_amdgcn_raw_buffer_load_i32x4(srd, voff, 0, CP_SC01));
}
static __device__ __forceinline__ void bstore(i32x4 srd, int voff, uint4 v) {
  llvm_amdgcn_raw_buffer_store_i32x4(__builtin_bit_cast(i32x4, v), srd, voff, 0, CP_SC01);
}

static __device__ __forceinline__ uint16_t f2b(float f) {
  union { float f; uint32_t u; } v; v.f = f;
  uint32_t r = (v.u + 0x7FFFu + ((v.u >> 16) & 1u)) >> 16;  // RNE
  return (uint16_t)r;
}
static __device__ __forceinline__ uint4 cvt8(const float* s) {
  uint4 o;
  o.x = (uint32_t)f2b(s[0]) | ((uint32_t)f2b(s[1]) << 16);
  o.y = (uint32_t)f2b(s[2]) | ((uint32_t)f2b(s[3]) << 16);
  o.z = (uint32_t)f2b(s[4]) | ((uint32_t)f2b(s[5]) << 16);
  o.w = (uint32_t)f2b(s[6]) | ((uint32_t)f2b(s[7]) << 16);
  return o;
}
static __device__ __forceinline__ f32x4 mfma16(uint4 a, uint4 b, f32x4 c) {
  return __builtin_amdgcn_mfma_f32_16x16x32_bf16(
      __builtin_bit_cast(bf16x8, a), __builtin_bit_cast(bf16x8, b), c, 0, 0, 0);
}
static __device__ __forceinline__ float sigm(float x)  { return 1.0f / (1.0f + __expf(-x)); }
static __device__ __forceinline__ float tanhx(float x) { return 1.0f - 2.0f / (__expf(2.0f * x) + 1.0f); }
static __device__ __forceinline__ int imin2(int a, int b) { return a < b ? a : b; }

#define FLD(i) ((int)__hip_atomic_load(fl + (i), __ATOMIC_RELAXED, __HIP_MEMORY_SCOPE_AGENT))
#define CROW 65   // padded cpart row stride in uint4 units (bank-conflict fix, R13-confirmed)

// ---------------- pack kernels (identical to R4-R11) ----------------
__global__ void pack_w0(const float* __restrict__ wih, const float* __restrict__ whh,
                        char* __restrict__ ws) {
  uint32_t u = blockIdx.x * blockDim.x + threadIdx.x;   // 786432
  int lane = u & 63;
  uint32_t idx = u >> 6;            // (bw*4 + w)*48 + j
  int j = (int)(idx % 48u);
  uint32_t r2 = idx / 48u;
  int w = r2 & 3, bw = r2 >> 2;
  int c = (j & 3) * 16 + (lane & 15);
  int g_row = (c & 3) * 1024 + bw * 16 + (c >> 2);
  uint4 v;
  if (j < 16) {
    int k = w * 128 + (j >> 2) * 32 + (lane >> 4) * 8;
    v = cvt8(wih + (size_t)g_row * 512 + k);
  } else {
    int k = w * 256 + ((j - 16) >> 2) * 32 + (lane >> 4) * 8;
    v = cvt8(whh + (size_t)g_row * 1024 + k);
  }
  ((uint4*)(ws + OFF_WP0))[u] = v;
}
__global__ void pack_w1(const float* __restrict__ wih, const float* __restrict__ whh,
                        char* __restrict__ ws) {
  uint32_t u = blockIdx.x * blockDim.x + threadIdx.x;   // 1048576
  int lane = u & 63;
  int j = (u >> 6) & 31;
  int w = (u >> 11) & 3;
  int bw = u >> 13;
  int c = (j & 1) * 16 + (lane & 15);
  int g_row = (c & 3) * 1024 + bw * 8 + (c >> 2);
  int k = w * 512 + (j >> 1) * 32 + (lane >> 4) * 8;
  uint4 v;
  if (k < 1024) v = cvt8(wih + (size_t)g_row * 1024 + k);
  else          v = cvt8(whh + (size_t)g_row * 1024 + (k - 1024));
  ((uint4*)(ws + OFF_WP1))[u] = v;
}
__global__ void pack_x(const float* __restrict__ x, char* __restrict__ ws) {
  uint32_t u = blockIdx.x * blockDim.x + threadIdx.x;   // 1048576
  int lane = u & 63;
  int F = (u >> 6) & 63;
  int t = u >> 12;
  int r = (F & 3) * 16 + (lane & 15);
  int k = (F >> 2) * 32 + (lane >> 4) * 8;
  ((uint4*)(ws + OFF_XP))[u] = cvt8(x + (size_t)r * (TT * CIN) + (size_t)t * CIN + k);
}
__global__ void pack_bias(const float* __restrict__ bih0, const float* __restrict__ bhh0,
                          const float* __restrict__ bih1, const float* __restrict__ bhh1,
                          char* __restrict__ ws) {
  uint32_t v = blockIdx.x * blockDim.x + threadIdx.x;   // 8192
  if (v < 4096) ((float*)(ws + OFF_B0S))[v] = bih0[v] + bhh0[v];
  else          ((float*)(ws + OFF_B1S))[v - 4096] = bih1[v - 4096] + bhh1[v - 4096];
}

// ---------------- group-split waits (R11-proven, byte-identical) ----------------
static __device__ __forceinline__ void wait_L0(uint32_t* fl, int tgt) {
  const int lane = threadIdx.x & 63;
  for (;;) {
    int f0 = FLD(lane);
    int f1 = FLD(64 + lane);
    int f2 = FLD(128 + lane);
    int mn1 = imin2(f1, f2);
    if (__all(f0 >= tgt && mn1 >= tgt - 2)) break;
    __builtin_amdgcn_s_sleep(1);
  }
  __builtin_amdgcn_fence(__ATOMIC_ACQUIRE, "workgroup");
}
static __device__ __forceinline__ void wait_L1a(uint32_t* fl, int tgt) {
  const int lane = threadIdx.x & 63;
  for (;;) {
    int f0 = FLD(lane);
    if (__all(f0 >= tgt)) break;
    __builtin_amdgcn_s_sleep(1);
  }
  __builtin_amdgcn_fence(__ATOMIC_ACQUIRE, "workgroup");
}
static __device__ __forceinline__ void wait_L1b(uint32_t* fl, int tgt) {
  const int lane = threadIdx.x & 63;
  for (;;) {
    int f1 = FLD(64 + lane);
    int f2 = FLD(128 + lane);
    int mn = imin2(f1, f2);
    if (__all(mn >= tgt)) break;
    __builtin_amdgcn_s_sleep(1);
  }
  __builtin_amdgcn_fence(__ATOMIC_ACQUIRE, "workgroup");
}

// ---------------- persistent LSTM ----------------
// blocks 0..63: layer0, 16 units each; blocks 64..191: layer1, 8 units each.
// phase p: L0 computes t=p (p<256), L1 computes t=p-1 (p>=1).
// h rings: write slot p&3, read slot (p+3)&3. Transport: buffer dwordx4 sc0 sc1 (R11).
__global__ __launch_bounds__(NTHR, 1) void lstm_persist(char* __restrict__ ws,
                                                        float* __restrict__ out) {
  __shared__ float cpart[64 * CROW * 4];         // padded: 64 rows x 65 uint4 (~65 KB)
  __shared__ __align__(16) uint16_t hreg[1024];  // 2 KB staged h tile
  const int tid = threadIdx.x, blk = blockIdx.x;
  const int wave = tid >> 6, lane = tid & 63;
  const bool isL1 = blk >= 64;
  const int bw = isL1 ? blk - 64 : blk;
  uint32_t* flags = (uint32_t*)(ws + OFF_FLG);

  const int eu  = isL1 ? (tid & 7)  : (tid & 15);
  const int erb = isL1 ? (tid >> 3) : (tid >> 4);
  const int ug  = isL1 ? (bw * 8 + eu) : (bw * 16 + eu);
  const float* bsrc = (const float*)(ws + (isL1 ? OFF_B1S : OFF_B0S));
  const float bs0 = bsrc[ug], bs1 = bsrc[1024 + ug], bs2 = bsrc[2048 + ug], bs3 = bsrc[3072 + ug];
  float cst[4] = {0.f, 0.f, 0.f, 0.f};

  // ---- persistent register-resident weights (R11: full b[48] for L0) ----
  uint4 b[48];
  if (isL1) {
    const uint4* bp = (const uint4*)(ws + OFF_WP1) + ((size_t)(bw * 4 + wave) * 32) * 64 + lane;
    #pragma unroll
    for (int j = 0; j < 32; ++j) b[j] = bp[(size_t)j * 64];
  } else {
    const uint4* bp = (const uint4*)(ws + OFF_WP0) + ((size_t)(bw * 4 + wave) * 48) * 64 + lane;
    #pragma unroll
    for (int j = 0; j < 48; ++j) b[j] = bp[(size_t)j * 64];
  }

  for (int p = 0; p <= 256; ++p) {
    f32x4 acc[4][4];
    #pragma unroll
    for (int rf = 0; rf < 4; ++rf)
      #pragma unroll
      for (int cf = 0; cf < 4; ++cf)
        acc[rf][cf] = (f32x4){0.f, 0.f, 0.f, 0.f};

    if (!isL1) {
      if (p == 256) break;     // flag 256 already published after p=255
      // x-part first (plain cached loads): independent of flags, hides wait
      const uint4* xpl = (const uint4*)(ws + OFF_XP) + (size_t)p * 4096 + lane;
      #pragma unroll
      for (int jx = 0; jx < 4; ++jx) {
        const int kf = wave * 4 + jx;
        uint4 a0 = xpl[kf * 256], a1 = xpl[kf * 256 + 64],
              a2 = xpl[kf * 256 + 128], a3 = xpl[kf * 256 + 192];
        #pragma unroll
        for (int cf = 0; cf < 4; ++cf) {
          uint4 bb = b[jx * 4 + cf];
          acc[0][cf] = mfma16(a0, bb, acc[0][cf]);
          acc[1][cf] = mfma16(a1, bb, acc[1][cf]);
          acc[2][cf] = mfma16(a2, bb, acc[2][cf]);
          acc[3][cf] = mfma16(a3, bb, acc[3][cf]);
        }
      }
      if (p > 0) wait_L0(flags, p);
      const i32x4 srdh = make_srd(ws + OFF_H0 + (size_t)((p + 3) & 3) * SZ_HP);
      #pragma unroll
      for (int jh = 0; jh < 8; ++jh) {
        const int kf = wave * 8 + jh;
        const int base = (kf * 256 + lane) * 16;
        uint4 a0 = bload(srdh, base);
        uint4 a1 = bload(srdh, base + 64 * 16);
        uint4 a2 = bload(srdh, base + 128 * 16);
        uint4 a3 = bload(srdh, base + 192 * 16);
        #pragma unroll
        for (int cf = 0; cf < 4; ++cf) {
          uint4 bb = b[16 + jh * 4 + cf];
          acc[0][cf] = mfma16(a0, bb, acc[0][cf]);
          acc[1][cf] = mfma16(a1, bb, acc[1][cf]);
          acc[2][cf] = mfma16(a2, bb, acc[2][cf]);
          acc[3][cf] = mfma16(a3, bb, acc[3][cf]);
        }
      }
    } else {
      if (p == 0) {
        if (tid == 0)
          __hip_atomic_store(flags + blk, 1u, __ATOMIC_RELAXED, __HIP_MEMORY_SCOPE_AGENT);
        continue;
      }
      // per-wave waits: waves 0,1 read h0 (need L0 group), waves 2,3 read h1 (own group)
      if (wave < 2) wait_L1a(flags, p);
      else          wait_L1b(flags, p);
      uint32_t boff = (uint32_t)(wave < 2 ? OFF_H0 : OFF_H1) + ((p + 3) & 3) * (uint32_t)SZ_HP;
      boff = __builtin_amdgcn_readfirstlane(boff);          // SRD must be scalar
      const i32x4 srdh = make_srd(ws + boff);
      const int kb = (wave & 1) * 16;
      #pragma unroll
      for (int jh = 0; jh < 16; ++jh) {
        const int kf = kb + jh;
        const int base = (kf * 256 + lane) * 16;
        uint4 a0 = bload(srdh, base);
        uint4 a1 = bload(srdh, base + 64 * 16);
        uint4 a2 = bload(srdh, base + 128 * 16);
        uint4 a3 = bload(srdh, base + 192 * 16);
        #pragma unroll
        for (int cf = 0; cf < 2; ++cf) {
          uint4 bb = b[jh * 2 + cf];
          acc[0][cf] = mfma16(a0, bb, acc[0][cf]);
          acc[1][cf] = mfma16(a1, bb, acc[1][cf]);
          acc[2][cf] = mfma16(a2, bb, acc[2][cf]);
          acc[3][cf] = mfma16(a3, bb, acc[3][cf]);
        }
      }
    }

    // ---- stash K-quarter partials (padded rows: stride CROW uint4) ----
    if (isL1) {
      #pragma unroll
      for (int rf = 0; rf < 4; ++rf)
        #pragma unroll
        for (int cf = 0; cf < 2; ++cf)
          *(f32x4*)&cpart[(((wave * 4 + rf) * 2 + cf) * CROW + lane) * 4] = acc[rf][cf];
    } else {
      #pragma unroll
      for (int rf = 0; rf < 4; ++rf)
        #pragma unroll
        for (int cf = 0; cf < 4; ++cf)
          *(f32x4*)&cpart[(((wave * 4 + rf) * 4 + cf) * CROW + lane) * 4] = acc[rf][cf];
    }
    __syncthreads();

    // ---- reduce + elementwise (c-state in f32 registers) ----
    if (isL1) {
      #pragma unroll
      for (int half = 0; half < 2; ++half) {
        const int r64 = erb + half * 32;
        const int rf = r64 >> 4, r16 = r64 & 15;
        const int reg = r16 & 3, lbase = 16 * (r16 >> 2);
        float gs[4];
        #pragma unroll
        for (int g = 0; g < 4; ++g) {
          const int c = eu * 4 + g;
          const int lc = (c & 15) + lbase;
          const int cf = c >> 4;
          float s = 0.f;
          #pragma unroll
          for (int w = 0; w < 4; ++w)
            s += cpart[(((w * 4 + rf) * 2 + cf) * CROW + lc) * 4 + reg];
          gs[g] = s;
        }
        const float iv = sigm(gs[0] + bs0), fv = sigm(gs[1] + bs1);
        const float gv = tanhx(gs[2] + bs2), ov = sigm(gs[3] + bs3);
        float cs = cst[half];
        cs = fv * cs + iv * gv;
        cst[half] = cs;
        const float hv = ov * tanhx(cs);
        hreg[r64 * 8 + eu] = f2b(hv);
        if (p == 256) out[(size_t)r64 * 1024 + ug] = hv;
      }
    } else {
      #pragma unroll
      for (int half = 0; half < 4; ++half) {
        const int r64 = erb + half * 16;      // erb < 16
        const int rf = half, r16 = erb;
        const int reg = r16 & 3, lbase = 16 * (r16 >> 2);
        float gs[4];
        #pragma unroll
        for (int g = 0; g < 4; ++g) {
          const int c = eu * 4 + g;           // [0,64)
          const int lc = (c & 15) + lbase;
          const int cf = c >> 4;
          float s = 0.f;
          #pragma unroll
          for (int w = 0; w < 4; ++w)
            s += cpart[(((w * 4 + rf) * 4 + cf) * CROW + lc) * 4 + reg];
          gs[g] = s;
        }
        const float iv = sigm(gs[0] + bs0), fv = sigm(gs[1] + bs1);
        const float gv = tanhx(gs[2] + bs2), ov = sigm(gs[3] + bs3);
        float cs = cst[half];
        cs = fv * cs + iv * gv;
        cst[half] = cs;
        const float hv = ov * tanhx(cs);
        hreg[r64 * 16 + eu] = f2b(hv);
      }
    }
    __syncthreads();

    // ---- publish h: buffer_store_dwordx4 sc0 sc1 -> barrier (drains vmcnt) -> flag ----
    if (p < 256) {
      if (isL1) {
        if (tid < 64) {
          uint4 v = ((const uint4*)hreg)[tid];          // row tid, units bw*8..+7
          const i32x4 srdw = make_srd(ws + OFF_H1 + (size_t)(p & 3) * SZ_HP);
          const int off = ((bw >> 2) * 4 + (tid >> 4)) * 1024 + (bw & 3) * 256 + (tid & 15) * 16;
          bstore(srdw, off, v);
        }
      } else {
        if (tid < 128) {
          uint4 v = ((const uint4*)hreg)[tid];          // row tid>>1, units (tid&1)*8..+8
          const i32x4 srdw = make_srd(ws + OFF_H0 + (size_t)(p & 3) * SZ_HP);
          const int off = ((bw >> 1) * 4 + (tid >> 5)) * 1024
                        + (2 * (bw & 1) + (tid & 1)) * 256 + ((tid >> 1) & 15) * 16;
          bstore(srdw, off, v);
        }
      }
      __syncthreads();   // each wave's s_waitcnt vmcnt(0) before s_barrier -> stores complete
      if (tid == 0)
        __hip_atomic_store(flags + blk, (uint32_t)(p + 1), __ATOMIC_RELAXED, __HIP_MEMORY_SCOPE_AGENT);
    }
  }
}

// ---------------- launcher ----------------
extern "C" void kernel_launch(void* const* d_in, const int* in_sizes, int n_in,
                              void* d_out, int out_size, void* d_ws, size_t ws_size,
                              hipStream_t stream) {
  const float* x    = (const float*)d_in[0];
  const float* Wih0 = (const float*)d_in[1];
  const float* Whh0 = (const float*)d_in[2];
  const float* bih0 = (const float*)d_in[3];
  const float* bhh0 = (const float*)d_in[4];
  const float* Wih1 = (const float*)d_in[5];
  const float* Whh1 = (const float*)d_in[6];
  const float* bih1 = (const float*)d_in[7];
  const float* bhh1 = (const float*)d_in[8];
  char* ws = (char*)d_ws;
  float* out = (float*)d_out;

  // zero h rings + flags (re-runs on every graph replay)
  hipMemsetAsync(ws + OFF_H0, 0, ZERO_SZ, stream);

  pack_w0  <<<3072, 256, 0, stream>>>(Wih0, Whh0, ws);
  pack_w1  <<<4096, 256, 0, stream>>>(Wih1, Whh1, ws);
  pack_x   <<<4096, 256, 0, stream>>>(x, ws);
  pack_bias<<<32,   256, 0, stream>>>(bih0, bhh0, bih1, bhh1, ws);

  void* args[] = {(void*)&ws, (void*)&out};
  hipError_t e = hipLaunchCooperativeKernel((const void*)lstm_persist, dim3(NBLK),
                                            dim3(NTHR), args, 0, stream);
  if (e != hipSuccess) {
    (void)hipGetLastError();   // clear sticky error; fall back to plain launch
    lstm_persist<<<dim3(NBLK), dim3(NTHR), 0, stream>>>(ws, out);
  }
}

// Round 16
// 1931.828 us; speedup vs baseline: 1.3708x; 1.0087x over previous
//
#include <hip/hip_runtime.h>
#include <stdint.h>

// ---------------- problem dims ----------------
#define BB   64
#define TT   256
#define CIN  512
#define HH   1024
#define NBLK 192     // 64 L0 blocks (16 units) + 128 L1 blocks (8 units)
#define NTHR 256

// ---------------- workspace layout (bytes) ----------------
#define OFF_WP0 0ull                 // 64*4*48*64*16 = 12 MB   [bw][wave][j48][lane][16B]
#define OFF_WP1 12582912ull          // 128*4*32*64*16 = 16 MB  [bw][wave][j32][lane][16B]
#define OFF_XP  29360128ull          // [t256][F64][lane][16B] = 16 MB
#define OFF_B0S 46137344ull          // 4096 f32 (bih0+bhh0)
#define OFF_B1S 46153728ull          // 4096 f32
#define OFF_H0  46170112ull          // 4 x 128 KB ring
#define OFF_H1  46694400ull          // 4 x 128 KB ring
#define OFF_FLG 47218688ull          // 192 u32 flags (0..63 = L0, 64..191 = L1)
#define SZ_HP   131072ull
#define ZERO_SZ (8*SZ_HP + 1024)

typedef short bf16x8 __attribute__((ext_vector_type(8)));
typedef float f32x4 __attribute__((ext_vector_type(4)));
typedef int   i32x4 __attribute__((ext_vector_type(4)));

__device__ i32x4 llvm_amdgcn_raw_buffer_load_i32x4(i32x4 srsrc, int voffset, int soffset,
                                                   int cachepolicy) __asm("llvm.amdgcn.raw.buffer.load.v4i32");
__device__ void  llvm_amdgcn_raw_buffer_store_i32x4(i32x4 vdata, i32x4 srsrc, int voffset,
                                                    int soffset, int cachepolicy) __asm("llvm.amdgcn.raw.buffer.store.v4i32");
#define CP_SC01 17   // sc0|sc1: device-coherent, L1/L2-bypass (R11-proven)

static __device__ __forceinline__ i32x4 make_srd(const char* p) {
  i32x4 r;
  r.x = (int)(uint32_t)(uintptr_t)p;
  r.y = (int)(uint32_t)((uintptr_t)p >> 32);
  r.z = (int)0xFFFFFFFF;
  r.w = 0x00020000;
  return r;
}
static __device__ __forceinline__ uint4 bload(i32x4 srd, int voff) {
  return __builtin_bit_cast(uint4, llvm_amdgcn_raw_buffer_load_i32x4(srd, voff, 0, CP_SC01));
}
static __device__ __forceinline__ void bstore(i32x4 srd, int voff, uint4 v) {
  llvm_amdgcn_raw_buffer_store_i32x4(__builtin_bit_cast(i32x4, v), srd, voff, 0, CP_SC01);
}

static __device__ __forceinline__ uint16_t f2b(float f) {
  union { float f; uint32_t u; } v; v.f = f;
  uint32_t r = (v.u + 0x7FFFu + ((v.u >> 16) & 1u)) >> 16;  // RNE
  return (uint16_t)r;
}
static __device__ __forceinline__ uint4 cvt8(const float* s) {
  uint4 o;
  o.x = (uint32_t)f2b(s[0]) | ((uint32_t)f2b(s[1]) << 16);
  o.y = (uint32_t)f2b(s[2]) | ((uint32_t)f2b(s[3]) << 16);
  o.z = (uint32_t)f2b(s[4]) | ((uint32_t)f2b(s[5]) << 16);
  o.w = (uint32_t)f2b(s[6]) | ((uint32_t)f2b(s[7]) << 16);
  return o;
}
static __device__ __forceinline__ f32x4 mfma16(uint4 a, uint4 b, f32x4 c) {
  return __builtin_amdgcn_mfma_f32_16x16x32_bf16(
      __builtin_bit_cast(bf16x8, a), __builtin_bit_cast(bf16x8, b), c, 0, 0, 0);
}
static __device__ __forceinline__ float sigm(float x)  { return 1.0f / (1.0f + __expf(-x)); }
static __device__ __forceinline__ float tanhx(float x) { return 1.0f - 2.0f / (__expf(2.0f * x) + 1.0f); }
static __device__ __forceinline__ int imin2(int a, int b) { return a < b ? a : b; }

#define FLD(i) ((int)__hip_atomic_load(fl + (i), __ATOMIC_RELAXED, __HIP_MEMORY_SCOPE_AGENT))
#define CROW 65   // padded cpart row stride in uint4 units (bank-conflict fix, R13-confirmed)

// R16: hard anti-hoist boundary after each poll — speculatable buffer loads must not
// be scheduled above the flag observation (rule-#18 pattern; fixes R11/R14/R15
// scheduling-dependent stale reads).
static __device__ __forceinline__ void load_fence() {
  __builtin_amdgcn_fence(__ATOMIC_ACQUIRE, "workgroup");
  __builtin_amdgcn_sched_barrier(0);
  asm volatile("" ::: "memory");
}

// ---------------- pack kernels (identical to R4-R14) ----------------
__global__ void pack_w0(const float* __restrict__ wih, const float* __restrict__ whh,
                        char* __restrict__ ws) {
  uint32_t u = blockIdx.x * blockDim.x + threadIdx.x;   // 786432
  int lane = u & 63;
  uint32_t idx = u >> 6;            // (bw*4 + w)*48 + j
  int j = (int)(idx % 48u);
  uint32_t r2 = idx / 48u;
  int w = r2 & 3, bw = r2 >> 2;
  int c = (j & 3) * 16 + (lane & 15);
  int g_row = (c & 3) * 1024 + bw * 16 + (c >> 2);
  uint4 v;
  if (j < 16) {
    int k = w * 128 + (j >> 2) * 32 + (lane >> 4) * 8;
    v = cvt8(wih + (size_t)g_row * 512 + k);
  } else {
    int k = w * 256 + ((j - 16) >> 2) * 32 + (lane >> 4) * 8;
    v = cvt8(whh + (size_t)g_row * 1024 + k);
  }
  ((uint4*)(ws + OFF_WP0))[u] = v;
}
__global__ void pack_w1(const float* __restrict__ wih, const float* __restrict__ whh,
                        char* __restrict__ ws) {
  uint32_t u = blockIdx.x * blockDim.x + threadIdx.x;   // 1048576
  int lane = u & 63;
  int j = (u >> 6) & 31;
  int w = (u >> 11) & 3;
  int bw = u >> 13;
  int c = (j & 1) * 16 + (lane & 15);
  int g_row = (c & 3) * 1024 + bw * 8 + (c >> 2);
  int k = w * 512 + (j >> 1) * 32 + (lane >> 4) * 8;
  uint4 v;
  if (k < 1024) v = cvt8(wih + (size_t)g_row * 1024 + k);
  else          v = cvt8(whh + (size_t)g_row * 1024 + (k - 1024));
  ((uint4*)(ws + OFF_WP1))[u] = v;
}
__global__ void pack_x(const float* __restrict__ x, char* __restrict__ ws) {
  uint32_t u = blockIdx.x * blockDim.x + threadIdx.x;   // 1048576
  int lane = u & 63;
  int F = (u >> 6) & 63;
  int t = u >> 12;
  int r = (F & 3) * 16 + (lane & 15);
  int k = (F >> 2) * 32 + (lane >> 4) * 8;
  ((uint4*)(ws + OFF_XP))[u] = cvt8(x + (size_t)r * (TT * CIN) + (size_t)t * CIN + k);
}
__global__ void pack_bias(const float* __restrict__ bih0, const float* __restrict__ bhh0,
                          const float* __restrict__ bih1, const float* __restrict__ bhh1,
                          char* __restrict__ ws) {
  uint32_t v = blockIdx.x * blockDim.x + threadIdx.x;   // 8192
  if (v < 4096) ((float*)(ws + OFF_B0S))[v] = bih0[v] + bhh0[v];
  else          ((float*)(ws + OFF_B1S))[v - 4096] = bih1[v - 4096] + bhh1[v - 4096];
}

// ---------------- group-split waits (R11 logic + R16 anti-hoist) ----------------
static __device__ __forceinline__ void wait_L0(uint32_t* fl, int tgt) {
  const int lane = threadIdx.x & 63;
  for (;;) {
    int f0 = FLD(lane);
    int f1 = FLD(64 + lane);
    int f2 = FLD(128 + lane);
    int mn1 = imin2(f1, f2);
    if (__all(f0 >= tgt && mn1 >= tgt - 2)) break;
    __builtin_amdgcn_s_sleep(1);
  }
  load_fence();
}
static __device__ __forceinline__ void wait_L1a(uint32_t* fl, int tgt) {
  const int lane = threadIdx.x & 63;
  for (;;) {
    int f0 = FLD(lane);
    if (__all(f0 >= tgt)) break;
    __builtin_amdgcn_s_sleep(1);
  }
  load_fence();
}
static __device__ __forceinline__ void wait_L1b(uint32_t* fl, int tgt) {
  const int lane = threadIdx.x & 63;
  for (;;) {
    int f1 = FLD(64 + lane);
    int f2 = FLD(128 + lane);
    int mn = imin2(f1, f2);
    if (__all(mn >= tgt)) break;
    __builtin_amdgcn_s_sleep(1);
  }
  load_fence();
}

// ---------------- persistent LSTM ----------------
// blocks 0..63: layer0, 16 units each; blocks 64..191: layer1, 8 units each.
// phase p: L0 computes t=p (p<256), L1 computes t=p-1 (p>=1).
// h rings: write slot p&3, read slot (p+3)&3. Transport: buffer dwordx4 sc0 sc1 (R11).
__global__ __launch_bounds__(NTHR, 1) void lstm_persist(char* __restrict__ ws,
                                                        float* __restrict__ out) {
  __shared__ float cpart[64 * CROW * 4];         // padded: 64 rows x 65 uint4 (~65 KB)
  __shared__ __align__(16) uint16_t hreg[1024];  // 2 KB staged h tile
  const int tid = threadIdx.x, blk = blockIdx.x;
  const int wave = tid >> 6, lane = tid & 63;
  const bool isL1 = blk >= 64;
  const int bw = isL1 ? blk - 64 : blk;
  uint32_t* flags = (uint32_t*)(ws + OFF_FLG);

  const int eu  = isL1 ? (tid & 7)  : (tid & 15);
  const int erb = isL1 ? (tid >> 3) : (tid >> 4);
  const int ug  = isL1 ? (bw * 8 + eu) : (bw * 16 + eu);
  const float* bsrc = (const float*)(ws + (isL1 ? OFF_B1S : OFF_B0S));
  const float bs0 = bsrc[ug], bs1 = bsrc[1024 + ug], bs2 = bsrc[2048 + ug], bs3 = bsrc[3072 + ug];
  float cst[4] = {0.f, 0.f, 0.f, 0.f};

  // ---- persistent register-resident weights (R11: full b[48] for L0) ----
  uint4 b[48];
  if (isL1) {
    const uint4* bp = (const uint4*)(ws + OFF_WP1) + ((size_t)(bw * 4 + wave) * 32) * 64 + lane;
    #pragma unroll
    for (int j = 0; j < 32; ++j) b[j] = bp[(size_t)j * 64];
  } else {
    const uint4* bp = (const uint4*)(ws + OFF_WP0) + ((size_t)(bw * 4 + wave) * 48) * 64 + lane;
    #pragma unroll
    for (int j = 0; j < 48; ++j) b[j] = bp[(size_t)j * 64];
  }

  for (int p = 0; p <= 256; ++p) {
    f32x4 acc[4][4];
    #pragma unroll
    for (int rf = 0; rf < 4; ++rf)
      #pragma unroll
      for (int cf = 0; cf < 4; ++cf)
        acc[rf][cf] = (f32x4){0.f, 0.f, 0.f, 0.f};

    if (!isL1) {
      if (p == 256) break;     // flag 256 already published after p=255
      // x-part first (plain cached loads): independent of flags, hides wait
      const uint4* xpl = (const uint4*)(ws + OFF_XP) + (size_t)p * 4096 + lane;
      #pragma unroll
      for (int jx = 0; jx < 4; ++jx) {
        const int kf = wave * 4 + jx;
        uint4 a0 = xpl[kf * 256], a1 = xpl[kf * 256 + 64],
              a2 = xpl[kf * 256 + 128], a3 = xpl[kf * 256 + 192];
        #pragma unroll
        for (int cf = 0; cf < 4; ++cf) {
          uint4 bb = b[jx * 4 + cf];
          acc[0][cf] = mfma16(a0, bb, acc[0][cf]);
          acc[1][cf] = mfma16(a1, bb, acc[1][cf]);
          acc[2][cf] = mfma16(a2, bb, acc[2][cf]);
          acc[3][cf] = mfma16(a3, bb, acc[3][cf]);
        }
      }
      if (p > 0) wait_L0(flags, p);
      const i32x4 srdh = make_srd(ws + OFF_H0 + (size_t)((p + 3) & 3) * SZ_HP);
      #pragma unroll
      for (int jh = 0; jh < 8; ++jh) {
        const int kf = wave * 8 + jh;
        const int base = (kf * 256 + lane) * 16;
        uint4 a0 = bload(srdh, base);
        uint4 a1 = bload(srdh, base + 64 * 16);
        uint4 a2 = bload(srdh, base + 128 * 16);
        uint4 a3 = bload(srdh, base + 192 * 16);
        #pragma unroll
        for (int cf = 0; cf < 4; ++cf) {
          uint4 bb = b[16 + jh * 4 + cf];
          acc[0][cf] = mfma16(a0, bb, acc[0][cf]);
          acc[1][cf] = mfma16(a1, bb, acc[1][cf]);
          acc[2][cf] = mfma16(a2, bb, acc[2][cf]);
          acc[3][cf] = mfma16(a3, bb, acc[3][cf]);
        }
      }
    } else {
      if (p == 0) {
        if (tid == 0)
          __hip_atomic_store(flags + blk, 1u, __ATOMIC_RELAXED, __HIP_MEMORY_SCOPE_AGENT);
        continue;
      }
      // per-wave waits: waves 0,1 read h0 (need L0 group), waves 2,3 read h1 (own group)
      if (wave < 2) wait_L1a(flags, p);
      else          wait_L1b(flags, p);
      uint32_t boff = (uint32_t)(wave < 2 ? OFF_H0 : OFF_H1) + ((p + 3) & 3) * (uint32_t)SZ_HP;
      boff = __builtin_amdgcn_readfirstlane(boff);          // SRD must be scalar
      const i32x4 srdh = make_srd(ws + boff);
      const int kb = (wave & 1) * 16;
      #pragma unroll
      for (int jh = 0; jh < 16; ++jh) {
        const int kf = kb + jh;
        const int base = (kf * 256 + lane) * 16;
        uint4 a0 = bload(srdh, base);
        uint4 a1 = bload(srdh, base + 64 * 16);
        uint4 a2 = bload(srdh, base + 128 * 16);
        uint4 a3 = bload(srdh, base + 192 * 16);
        #pragma unroll
        for (int cf = 0; cf < 2; ++cf) {
          uint4 bb = b[jh * 2 + cf];
          acc[0][cf] = mfma16(a0, bb, acc[0][cf]);
          acc[1][cf] = mfma16(a1, bb, acc[1][cf]);
          acc[2][cf] = mfma16(a2, bb, acc[2][cf]);
          acc[3][cf] = mfma16(a3, bb, acc[3][cf]);
        }
      }
    }

    // ---- stash K-quarter partials (padded rows: stride CROW uint4) ----
    if (isL1) {
      #pragma unroll
      for (int rf = 0; rf < 4; ++rf)
        #pragma unroll
        for (int cf = 0; cf < 2; ++cf)
          *(f32x4*)&cpart[(((wave * 4 + rf) * 2 + cf) * CROW + lane) * 4] = acc[rf][cf];
    } else {
      #pragma unroll
      for (int rf = 0; rf < 4; ++rf)
        #pragma unroll
        for (int cf = 0; cf < 4; ++cf)
          *(f32x4*)&cpart[(((wave * 4 + rf) * 4 + cf) * CROW + lane) * 4] = acc[rf][cf];
    }
    __syncthreads();

    // ---- reduce + elementwise (c-state in f32 registers) ----
    if (isL1) {
      #pragma unroll
      for (int half = 0; half < 2; ++half) {
        const int r64 = erb + half * 32;
        const int rf = r64 >> 4, r16 = r64 & 15;
        const int reg = r16 & 3, lbase = 16 * (r16 >> 2);
        float gs[4];
        #pragma unroll
        for (int g = 0; g < 4; ++g) {
          const int c = eu * 4 + g;
          const int lc = (c & 15) + lbase;
          const int cf = c >> 4;
          float s = 0.f;
          #pragma unroll
          for (int w = 0; w < 4; ++w)
            s += cpart[(((w * 4 + rf) * 2 + cf) * CROW + lc) * 4 + reg];
          gs[g] = s;
        }
        const float iv = sigm(gs[0] + bs0), fv = sigm(gs[1] + bs1);
        const float gv = tanhx(gs[2] + bs2), ov = sigm(gs[3] + bs3);
        float cs = cst[half];
        cs = fv * cs + iv * gv;
        cst[half] = cs;
        const float hv = ov * tanhx(cs);
        hreg[r64 * 8 + eu] = f2b(hv);
        if (p == 256) out[(size_t)r64 * 1024 + ug] = hv;
      }
    } else {
      #pragma unroll
      for (int half = 0; half < 4; ++half) {
        const int r64 = erb + half * 16;      // erb < 16
        const int rf = half, r16 = erb;
        const int reg = r16 & 3, lbase = 16 * (r16 >> 2);
        float gs[4];
        #pragma unroll
        for (int g = 0; g < 4; ++g) {
          const int c = eu * 4 + g;           // [0,64)
          const int lc = (c & 15) + lbase;
          const int cf = c >> 4;
          float s = 0.f;
          #pragma unroll
          for (int w = 0; w < 4; ++w)
            s += cpart[(((w * 4 + rf) * 4 + cf) * CROW + lc) * 4 + reg];
          gs[g] = s;
        }
        const float iv = sigm(gs[0] + bs0), fv = sigm(gs[1] + bs1);
        const float gv = tanhx(gs[2] + bs2), ov = sigm(gs[3] + bs3);
        float cs = cst[half];
        cs = fv * cs + iv * gv;
        cst[half] = cs;
        const float hv = ov * tanhx(cs);
        hreg[r64 * 16 + eu] = f2b(hv);
      }
    }
    __syncthreads();

    // ---- publish h: buffer_store_dwordx4 sc0 sc1 -> barrier (drains vmcnt) -> flag ----
    if (p < 256) {
      if (isL1) {
        if (tid < 64) {
          uint4 v = ((const uint4*)hreg)[tid];          // row tid, units bw*8..+7
          const i32x4 srdw = make_srd(ws + OFF_H1 + (size_t)(p & 3) * SZ_HP);
          const int off = ((bw >> 2) * 4 + (tid >> 4)) * 1024 + (bw & 3) * 256 + (tid & 15) * 16;
          bstore(srdw, off, v);
        }
      } else {
        if (tid < 128) {
          uint4 v = ((const uint4*)hreg)[tid];          // row tid>>1, units (tid&1)*8..+8
          const i32x4 srdw = make_srd(ws + OFF_H0 + (size_t)(p & 3) * SZ_HP);
          const int off = ((bw >> 1) * 4 + (tid >> 5)) * 1024
                        + (2 * (bw & 1) + (tid & 1)) * 256 + ((tid >> 1) & 15) * 16;
          bstore(srdw, off, v);
        }
      }
      __syncthreads();   // each wave's s_waitcnt vmcnt(0) before s_barrier -> stores complete
      if (tid == 0)
        __hip_atomic_store(flags + blk, (uint32_t)(p + 1), __ATOMIC_RELAXED, __HIP_MEMORY_SCOPE_AGENT);
    }
  }
}

// ---------------- launcher ----------------
extern "C" void kernel_launch(void* const* d_in, const int* in_sizes, int n_in,
                              void* d_out, int out_size, void* d_ws, size_t ws_size,
                              hipStream_t stream) {
  const float* x    = (const float*)d_in[0];
  const float* Wih0 = (const float*)d_in[1];
  const float* Whh0 = (const float*)d_in[2];
  const float* bih0 = (const float*)d_in[3];
  const float* bhh0 = (const float*)d_in[4];
  const float* Wih1 = (const float*)d_in[5];
  const float* Whh1 = (const float*)d_in[6];
  const float* bih1 = (const float*)d_in[7];
  const float* bhh1 = (const float*)d_in[8];
  char* ws = (char*)d_ws;
  float* out = (float*)d_out;

  // zero h rings + flags (re-runs on every graph replay)
  hipMemsetAsync(ws + OFF_H0, 0, ZERO_SZ, stream);

  pack_w0  <<<3072, 256, 0, stream>>>(Wih0, Whh0, ws);
  pack_w1  <<<4096, 256, 0, stream>>>(Wih1, Whh1, ws);
  pack_x   <<<4096, 256, 0, stream>>>(x, ws);
  pack_bias<<<32,   256, 0, stream>>>(bih0, bhh0, bih1, bhh1, ws);

  void* args[] = {(void*)&ws, (void*)&out};
  hipError_t e = hipLaunchCooperativeKernel((const void*)lstm_persist, dim3(NBLK),
                                            dim3(NTHR), args, 0, stream);
  if (e != hipSuccess) {
    (void)hipGetLastError();   // clear sticky error; fall back to plain launch
    lstm_persist<<<dim3(NBLK), dim3(NTHR), 0, stream>>>(ws, out);
  }
}

// Round 17
// 1914.616 us; speedup vs baseline: 1.3831x; 1.0090x over previous
//
#include <hip/hip_runtime.h>
#include <stdint.h>

// ---------------- problem dims ----------------
#define BB   64
#define TT   256
#define CIN  512
#define HH   1024
#define NBLK 192     // 64 L0 blocks (16 units) + 128 L1 blocks (8 units)
#define NTHR 256

// ---------------- workspace layout (bytes) ----------------
#define OFF_WP0 0ull                 // 64*4*48*64*16 = 12 MB   [bw][wave][j48][lane][16B]
#define OFF_WP1 12582912ull          // 128*4*32*64*16 = 16 MB  [bw][wave][j32][lane][16B]
#define OFF_XP  29360128ull          // [t256][F64][lane][16B] = 16 MB
#define OFF_B0S 46137344ull          // 4096 f32 (bih0+bhh0)
#define OFF_B1S 46153728ull          // 4096 f32
#define OFF_H0  46170112ull          // 4 x 128 KB ring
#define OFF_H1  46694400ull          // 4 x 128 KB ring
#define OFF_FLG 47218688ull          // 192 u32 flags (0..63 = L0, 64..191 = L1)
#define SZ_HP   131072ull
#define ZERO_SZ (8*SZ_HP + 1024)

typedef short bf16x8 __attribute__((ext_vector_type(8)));
typedef float f32x4 __attribute__((ext_vector_type(4)));
typedef int   i32x4 __attribute__((ext_vector_type(4)));

__device__ i32x4 llvm_amdgcn_raw_buffer_load_i32x4(i32x4 srsrc, int voffset, int soffset,
                                                   int cachepolicy) __asm("llvm.amdgcn.raw.buffer.load.v4i32");
__device__ void  llvm_amdgcn_raw_buffer_store_i32x4(i32x4 vdata, i32x4 srsrc, int voffset,
                                                    int soffset, int cachepolicy) __asm("llvm.amdgcn.raw.buffer.store.v4i32");
#define CP_SC01 17   // sc0|sc1: device-coherent, L1/L2-bypass (R11-proven)

static __device__ __forceinline__ i32x4 make_srd(const char* p) {
  i32x4 r;
  r.x = (int)(uint32_t)(uintptr_t)p;
  r.y = (int)(uint32_t)((uintptr_t)p >> 32);
  r.z = (int)0xFFFFFFFF;
  r.w = 0x00020000;
  return r;
}
static __device__ __forceinline__ uint4 bload(i32x4 srd, int voff) {
  return __builtin_bit_cast(uint4, llvm_amdgcn_raw_buffer_load_i32x4(srd, voff, 0, CP_SC01));
}
static __device__ __forceinline__ void bstore(i32x4 srd, int voff, uint4 v) {
  llvm_amdgcn_raw_buffer_store_i32x4(__builtin_bit_cast(i32x4, v), srd, voff, 0, CP_SC01);
}

static __device__ __forceinline__ uint16_t f2b(float f) {
  union { float f; uint32_t u; } v; v.f = f;
  uint32_t r = (v.u + 0x7FFFu + ((v.u >> 16) & 1u)) >> 16;  // RNE
  return (uint16_t)r;
}
static __device__ __forceinline__ uint4 cvt8(const float* s) {
  uint4 o;
  o.x = (uint32_t)f2b(s[0]) | ((uint32_t)f2b(s[1]) << 16);
  o.y = (uint32_t)f2b(s[2]) | ((uint32_t)f2b(s[3]) << 16);
  o.z = (uint32_t)f2b(s[4]) | ((uint32_t)f2b(s[5]) << 16);
  o.w = (uint32_t)f2b(s[6]) | ((uint32_t)f2b(s[7]) << 16);
  return o;
}
static __device__ __forceinline__ f32x4 mfma16(uint4 a, uint4 b, f32x4 c) {
  return __builtin_amdgcn_mfma_f32_16x16x32_bf16(
      __builtin_bit_cast(bf16x8, a), __builtin_bit_cast(bf16x8, b), c, 0, 0, 0);
}
static __device__ __forceinline__ float sigm(float x)  { return 1.0f / (1.0f + __expf(-x)); }
static __device__ __forceinline__ float tanhx(float x) { return 1.0f - 2.0f / (__expf(2.0f * x) + 1.0f); }
static __device__ __forceinline__ int imin2(int a, int b) { return a < b ? a : b; }

#define FLD(i) ((int)__hip_atomic_load(fl + (i), __ATOMIC_RELAXED, __HIP_MEMORY_SCOPE_AGENT))
#define CROW 65   // padded cpart row stride in uint4 units (bank-conflict fix, R13-confirmed)

// R16-proven: hard anti-hoist boundary after each poll — buffer loads must not be
// scheduled above the flag observation (fixes scheduling-dependent stale reads).
static __device__ __forceinline__ void load_fence() {
  __builtin_amdgcn_fence(__ATOMIC_ACQUIRE, "workgroup");
  __builtin_amdgcn_sched_barrier(0);
  asm volatile("" ::: "memory");
}

// ---------------- pack kernels (identical to R4-R16) ----------------
__global__ void pack_w0(const float* __restrict__ wih, const float* __restrict__ whh,
                        char* __restrict__ ws) {
  uint32_t u = blockIdx.x * blockDim.x + threadIdx.x;   // 786432
  int lane = u & 63;
  uint32_t idx = u >> 6;            // (bw*4 + w)*48 + j
  int j = (int)(idx % 48u);
  uint32_t r2 = idx / 48u;
  int w = r2 & 3, bw = r2 >> 2;
  int c = (j & 3) * 16 + (lane & 15);
  int g_row = (c & 3) * 1024 + bw * 16 + (c >> 2);
  uint4 v;
  if (j < 16) {
    int k = w * 128 + (j >> 2) * 32 + (lane >> 4) * 8;
    v = cvt8(wih + (size_t)g_row * 512 + k);
  } else {
    int k = w * 256 + ((j - 16) >> 2) * 32 + (lane >> 4) * 8;
    v = cvt8(whh + (size_t)g_row * 1024 + k);
  }
  ((uint4*)(ws + OFF_WP0))[u] = v;
}
__global__ void pack_w1(const float* __restrict__ wih, const float* __restrict__ whh,
                        char* __restrict__ ws) {
  uint32_t u = blockIdx.x * blockDim.x + threadIdx.x;   // 1048576
  int lane = u & 63;
  int j = (u >> 6) & 31;
  int w = (u >> 11) & 3;
  int bw = u >> 13;
  int c = (j & 1) * 16 + (lane & 15);
  int g_row = (c & 3) * 1024 + bw * 8 + (c >> 2);
  int k = w * 512 + (j >> 1) * 32 + (lane >> 4) * 8;
  uint4 v;
  if (k < 1024) v = cvt8(wih + (size_t)g_row * 1024 + k);
  else          v = cvt8(whh + (size_t)g_row * 1024 + (k - 1024));
  ((uint4*)(ws + OFF_WP1))[u] = v;
}
__global__ void pack_x(const float* __restrict__ x, char* __restrict__ ws) {
  uint32_t u = blockIdx.x * blockDim.x + threadIdx.x;   // 1048576
  int lane = u & 63;
  int F = (u >> 6) & 63;
  int t = u >> 12;
  int r = (F & 3) * 16 + (lane & 15);
  int k = (F >> 2) * 32 + (lane >> 4) * 8;
  ((uint4*)(ws + OFF_XP))[u] = cvt8(x + (size_t)r * (TT * CIN) + (size_t)t * CIN + k);
}
__global__ void pack_bias(const float* __restrict__ bih0, const float* __restrict__ bhh0,
                          const float* __restrict__ bih1, const float* __restrict__ bhh1,
                          char* __restrict__ ws) {
  uint32_t v = blockIdx.x * blockDim.x + threadIdx.x;   // 8192
  if (v < 4096) ((float*)(ws + OFF_B0S))[v] = bih0[v] + bhh0[v];
  else          ((float*)(ws + OFF_B1S))[v - 4096] = bih1[v - 4096] + bhh1[v - 4096];
}

// ---------------- group-split waits (R16: poll + anti-hoist fence) ----------------
static __device__ __forceinline__ void wait_L0(uint32_t* fl, int tgt) {
  const int lane = threadIdx.x & 63;
  for (;;) {
    int f0 = FLD(lane);
    int f1 = FLD(64 + lane);
    int f2 = FLD(128 + lane);
    int mn1 = imin2(f1, f2);
    if (__all(f0 >= tgt && mn1 >= tgt - 2)) break;
    __builtin_amdgcn_s_sleep(1);
  }
  load_fence();
}
static __device__ __forceinline__ void wait_L1a(uint32_t* fl, int tgt) {
  const int lane = threadIdx.x & 63;
  for (;;) {
    int f0 = FLD(lane);
    if (__all(f0 >= tgt)) break;
    __builtin_amdgcn_s_sleep(1);
  }
  load_fence();
}
static __device__ __forceinline__ void wait_L1b(uint32_t* fl, int tgt) {
  const int lane = threadIdx.x & 63;
  for (;;) {
    int f1 = FLD(64 + lane);
    int f2 = FLD(128 + lane);
    int mn = imin2(f1, f2);
    if (__all(mn >= tgt)) break;
    __builtin_amdgcn_s_sleep(1);
  }
  load_fence();
}

// ---------------- persistent LSTM ----------------
// blocks 0..63: layer0, 16 units each; blocks 64..191: layer1, 8 units each.
// phase p: L0 computes t=p (p<256), L1 computes t=p-1 (p>=1).
// h rings: write slot p&3, read slot (p+3)&3. Transport: buffer dwordx4 sc0 sc1.
// R17: deep h-load prefetch (32 in flight) AFTER the fenced poll.
__global__ __launch_bounds__(NTHR, 1) void lstm_persist(char* __restrict__ ws,
                                                        float* __restrict__ out) {
  __shared__ float cpart[64 * CROW * 4];         // padded: 64 rows x 65 uint4 (~65 KB)
  __shared__ __align__(16) uint16_t hreg[1024];  // 2 KB staged h tile
  const int tid = threadIdx.x, blk = blockIdx.x;
  const int wave = tid >> 6, lane = tid & 63;
  const bool isL1 = blk >= 64;
  const int bw = isL1 ? blk - 64 : blk;
  uint32_t* flags = (uint32_t*)(ws + OFF_FLG);

  const int eu  = isL1 ? (tid & 7)  : (tid & 15);
  const int erb = isL1 ? (tid >> 3) : (tid >> 4);
  const int ug  = isL1 ? (bw * 8 + eu) : (bw * 16 + eu);
  const float* bsrc = (const float*)(ws + (isL1 ? OFF_B1S : OFF_B0S));
  const float bs0 = bsrc[ug], bs1 = bsrc[1024 + ug], bs2 = bsrc[2048 + ug], bs3 = bsrc[3072 + ug];
  float cst[4] = {0.f, 0.f, 0.f, 0.f};

  // ---- persistent register-resident weights (full b[48] for L0) ----
  uint4 b[48];
  if (isL1) {
    const uint4* bp = (const uint4*)(ws + OFF_WP1) + ((size_t)(bw * 4 + wave) * 32) * 64 + lane;
    #pragma unroll
    for (int j = 0; j < 32; ++j) b[j] = bp[(size_t)j * 64];
  } else {
    const uint4* bp = (const uint4*)(ws + OFF_WP0) + ((size_t)(bw * 4 + wave) * 48) * 64 + lane;
    #pragma unroll
    for (int j = 0; j < 48; ++j) b[j] = bp[(size_t)j * 64];
  }

  for (int p = 0; p <= 256; ++p) {
    f32x4 acc[4][4];
    #pragma unroll
    for (int rf = 0; rf < 4; ++rf)
      #pragma unroll
      for (int cf = 0; cf < 4; ++cf)
        acc[rf][cf] = (f32x4){0.f, 0.f, 0.f, 0.f};

    if (!isL1) {
      if (p == 256) break;     // flag 256 already published after p=255
      // x-part first (plain cached loads): independent of flags, hides wait
      const uint4* xpl = (const uint4*)(ws + OFF_XP) + (size_t)p * 4096 + lane;
      #pragma unroll
      for (int jx = 0; jx < 4; ++jx) {
        const int kf = wave * 4 + jx;
        uint4 a0 = xpl[kf * 256], a1 = xpl[kf * 256 + 64],
              a2 = xpl[kf * 256 + 128], a3 = xpl[kf * 256 + 192];
        #pragma unroll
        for (int cf = 0; cf < 4; ++cf) {
          uint4 bb = b[jx * 4 + cf];
          acc[0][cf] = mfma16(a0, bb, acc[0][cf]);
          acc[1][cf] = mfma16(a1, bb, acc[1][cf]);
          acc[2][cf] = mfma16(a2, bb, acc[2][cf]);
          acc[3][cf] = mfma16(a3, bb, acc[3][cf]);
        }
      }
      if (p > 0) wait_L0(flags, p);
      const i32x4 srdh = make_srd(ws + OFF_H0 + (size_t)((p + 3) & 3) * SZ_HP);
      // R17: issue ALL 32 h loads (post-fence) before first consumption
      uint4 av[32];
      #pragma unroll
      for (int jh = 0; jh < 8; ++jh) {
        const int base = ((wave * 8 + jh) * 256 + lane) * 16;
        av[jh * 4 + 0] = bload(srdh, base);
        av[jh * 4 + 1] = bload(srdh, base + 64 * 16);
        av[jh * 4 + 2] = bload(srdh, base + 128 * 16);
        av[jh * 4 + 3] = bload(srdh, base + 192 * 16);
      }
      #pragma unroll
      for (int jh = 0; jh < 8; ++jh) {
        uint4 a0 = av[jh * 4 + 0], a1 = av[jh * 4 + 1],
              a2 = av[jh * 4 + 2], a3 = av[jh * 4 + 3];
        #pragma unroll
        for (int cf = 0; cf < 4; ++cf) {
          uint4 bb = b[16 + jh * 4 + cf];
          acc[0][cf] = mfma16(a0, bb, acc[0][cf]);
          acc[1][cf] = mfma16(a1, bb, acc[1][cf]);
          acc[2][cf] = mfma16(a2, bb, acc[2][cf]);
          acc[3][cf] = mfma16(a3, bb, acc[3][cf]);
        }
      }
    } else {
      if (p == 0) {
        if (tid == 0)
          __hip_atomic_store(flags + blk, 1u, __ATOMIC_RELAXED, __HIP_MEMORY_SCOPE_AGENT);
        continue;
      }
      // per-wave waits: waves 0,1 read h0 (need L0 group), waves 2,3 read h1 (own group)
      if (wave < 2) wait_L1a(flags, p);
      else          wait_L1b(flags, p);
      uint32_t boff = (uint32_t)(wave < 2 ? OFF_H0 : OFF_H1) + ((p + 3) & 3) * (uint32_t)SZ_HP;
      boff = __builtin_amdgcn_readfirstlane(boff);          // SRD must be scalar
      const i32x4 srdh = make_srd(ws + boff);
      const int kb = (wave & 1) * 16;
      // R17: rotating 32-deep prefetch over the 16 jh groups (post-fence)
      uint4 av[32];
      #pragma unroll
      for (int jh = 0; jh < 8; ++jh) {
        const int base = ((kb + jh) * 256 + lane) * 16;
        av[jh * 4 + 0] = bload(srdh, base);
        av[jh * 4 + 1] = bload(srdh, base + 64 * 16);
        av[jh * 4 + 2] = bload(srdh, base + 128 * 16);
        av[jh * 4 + 3] = bload(srdh, base + 192 * 16);
      }
      #pragma unroll
      for (int jh = 0; jh < 16; ++jh) {
        const int s = jh & 7;
        uint4 a0 = av[s * 4 + 0], a1 = av[s * 4 + 1],
              a2 = av[s * 4 + 2], a3 = av[s * 4 + 3];
        if (jh < 8) {
          const int b2 = ((kb + jh + 8) * 256 + lane) * 16;
          av[s * 4 + 0] = bload(srdh, b2);
          av[s * 4 + 1] = bload(srdh, b2 + 64 * 16);
          av[s * 4 + 2] = bload(srdh, b2 + 128 * 16);
          av[s * 4 + 3] = bload(srdh, b2 + 192 * 16);
        }
        #pragma unroll
        for (int cf = 0; cf < 2; ++cf) {
          uint4 bb = b[jh * 2 + cf];
          acc[0][cf] = mfma16(a0, bb, acc[0][cf]);
          acc[1][cf] = mfma16(a1, bb, acc[1][cf]);
          acc[2][cf] = mfma16(a2, bb, acc[2][cf]);
          acc[3][cf] = mfma16(a3, bb, acc[3][cf]);
        }
      }
    }

    // ---- stash K-quarter partials (padded rows: stride CROW uint4) ----
    if (isL1) {
      #pragma unroll
      for (int rf = 0; rf < 4; ++rf)
        #pragma unroll
        for (int cf = 0; cf < 2; ++cf)
          *(f32x4*)&cpart[(((wave * 4 + rf) * 2 + cf) * CROW + lane) * 4] = acc[rf][cf];
    } else {
      #pragma unroll
      for (int rf = 0; rf < 4; ++rf)
        #pragma unroll
        for (int cf = 0; cf < 4; ++cf)
          *(f32x4*)&cpart[(((wave * 4 + rf) * 4 + cf) * CROW + lane) * 4] = acc[rf][cf];
    }
    __syncthreads();

    // ---- reduce + elementwise (c-state in f32 registers) ----
    if (isL1) {
      #pragma unroll
      for (int half = 0; half < 2; ++half) {
        const int r64 = erb + half * 32;
        const int rf = r64 >> 4, r16 = r64 & 15;
        const int reg = r16 & 3, lbase = 16 * (r16 >> 2);
        float gs[4];
        #pragma unroll
        for (int g = 0; g < 4; ++g) {
          const int c = eu * 4 + g;
          const int lc = (c & 15) + lbase;
          const int cf = c >> 4;
          float s = 0.f;
          #pragma unroll
          for (int w = 0; w < 4; ++w)
            s += cpart[(((w * 4 + rf) * 2 + cf) * CROW + lc) * 4 + reg];
          gs[g] = s;
        }
        const float iv = sigm(gs[0] + bs0), fv = sigm(gs[1] + bs1);
        const float gv = tanhx(gs[2] + bs2), ov = sigm(gs[3] + bs3);
        float cs = cst[half];
        cs = fv * cs + iv * gv;
        cst[half] = cs;
        const float hv = ov * tanhx(cs);
        hreg[r64 * 8 + eu] = f2b(hv);
        if (p == 256) out[(size_t)r64 * 1024 + ug] = hv;
      }
    } else {
      #pragma unroll
      for (int half = 0; half < 4; ++half) {
        const int r64 = erb + half * 16;      // erb < 16
        const int rf = half, r16 = erb;
        const int reg = r16 & 3, lbase = 16 * (r16 >> 2);
        float gs[4];
        #pragma unroll
        for (int g = 0; g < 4; ++g) {
          const int c = eu * 4 + g;           // [0,64)
          const int lc = (c & 15) + lbase;
          const int cf = c >> 4;
          float s = 0.f;
          #pragma unroll
          for (int w = 0; w < 4; ++w)
            s += cpart[(((w * 4 + rf) * 4 + cf) * CROW + lc) * 4 + reg];
          gs[g] = s;
        }
        const float iv = sigm(gs[0] + bs0), fv = sigm(gs[1] + bs1);
        const float gv = tanhx(gs[2] + bs2), ov = sigm(gs[3] + bs3);
        float cs = cst[half];
        cs = fv * cs + iv * gv;
        cst[half] = cs;
        const float hv = ov * tanhx(cs);
        hreg[r64 * 16 + eu] = f2b(hv);
      }
    }
    __syncthreads();

    // ---- publish h: buffer_store_dwordx4 sc0 sc1 -> barrier (drains vmcnt) -> flag ----
    if (p < 256) {
      if (isL1) {
        if (tid < 64) {
          uint4 v = ((const uint4*)hreg)[tid];          // row tid, units bw*8..+7
          const i32x4 srdw = make_srd(ws + OFF_H1 + (size_t)(p & 3) * SZ_HP);
          const int off = ((bw >> 2) * 4 + (tid >> 4)) * 1024 + (bw & 3) * 256 + (tid & 15) * 16;
          bstore(srdw, off, v);
        }
      } else {
        if (tid < 128) {
          uint4 v = ((const uint4*)hreg)[tid];          // row tid>>1, units (tid&1)*8..+8
          const i32x4 srdw = make_srd(ws + OFF_H0 + (size_t)(p & 3) * SZ_HP);
          const int off = ((bw >> 1) * 4 + (tid >> 5)) * 1024
                        + (2 * (bw & 1) + (tid & 1)) * 256 + ((tid >> 1) & 15) * 16;
          bstore(srdw, off, v);
        }
      }
      __syncthreads();   // each wave's s_waitcnt vmcnt(0) before s_barrier -> stores complete
      if (tid == 0)
        __hip_atomic_store(flags + blk, (uint32_t)(p + 1), __ATOMIC_RELAXED, __HIP_MEMORY_SCOPE_AGENT);
    }
  }
}

// ---------------- launcher ----------------
extern "C" void kernel_launch(void* const* d_in, const int* in_sizes, int n_in,
                              void* d_out, int out_size, void* d_ws, size_t ws_size,
                              hipStream_t stream) {
  const float* x    = (const float*)d_in[0];
  const float* Wih0 = (const float*)d_in[1];
  const float* Whh0 = (const float*)d_in[2];
  const float* bih0 = (const float*)d_in[3];
  const float* bhh0 = (const float*)d_in[4];
  const float* Wih1 = (const float*)d_in[5];
  const float* Whh1 = (const float*)d_in[6];
  const float* bih1 = (const float*)d_in[7];
  const float* bhh1 = (const float*)d_in[8];
  char* ws = (char*)d_ws;
  float* out = (float*)d_out;

  // zero h rings + flags (re-runs on every graph replay)
  hipMemsetAsync(ws + OFF_H0, 0, ZERO_SZ, stream);

  pack_w0  <<<3072, 256, 0, stream>>>(Wih0, Whh0, ws);
  pack_w1  <<<4096, 256, 0, stream>>>(Wih1, Whh1, ws);
  pack_x   <<<4096, 256, 0, stream>>>(x, ws);
  pack_bias<<<32,   256, 0, stream>>>(bih0, bhh0, bih1, bhh1, ws);

  void* args[] = {(void*)&ws, (void*)&out};
  hipError_t e = hipLaunchCooperativeKernel((const void*)lstm_persist, dim3(NBLK),
                                            dim3(NTHR), args, 0, stream);
  if (e != hipSuccess) {
    (void)hipGetLastError();   // clear sticky error; fall back to plain launch
    lstm_persist<<<dim3(NBLK), dim3(NTHR), 0, stream>>>(ws, out);
  }
}

// Round 18
// 1876.414 us; speedup vs baseline: 1.4113x; 1.0204x over previous
//
#include <hip/hip_runtime.h>
#include <stdint.h>

// ---------------- problem dims ----------------
#define BB   64
#define TT   256
#define CIN  512
#define HH   1024
#define NBLK 192     // 64 L0 blocks (16 units) + 128 L1 blocks (8 units)
#define NTHR 256

// ---------------- workspace layout (bytes) ----------------
#define OFF_WP0 0ull                 // 64*4*48*64*16 = 12 MB   [bw][wave][j48][lane][16B]
#define OFF_WP1 12582912ull          // 128*4*32*64*16 = 16 MB  [bw][wave][j32][lane][16B]
#define OFF_XP  29360128ull          // [t256][F64][lane][16B] = 16 MB
#define OFF_B0S 46137344ull          // 4096 f32 (bih0+bhh0)
#define OFF_B1S 46153728ull          // 4096 f32
#define OFF_H0  46170112ull          // 4 x 128 KB ring
#define OFF_H1  46694400ull          // 4 x 128 KB ring
#define OFF_FLG 47218688ull          // 192 u32 flags (0..63 = L0, 64..191 = L1)
#define SZ_HP   131072ull
#define ZERO_SZ (8*SZ_HP + 1024)

typedef short bf16x8 __attribute__((ext_vector_type(8)));
typedef float f32x4 __attribute__((ext_vector_type(4)));
typedef int   i32x4 __attribute__((ext_vector_type(4)));

__device__ i32x4 llvm_amdgcn_raw_buffer_load_i32x4(i32x4 srsrc, int voffset, int soffset,
                                                   int cachepolicy) __asm("llvm.amdgcn.raw.buffer.load.v4i32");
__device__ void  llvm_amdgcn_raw_buffer_store_i32x4(i32x4 vdata, i32x4 srsrc, int voffset,
                                                    int soffset, int cachepolicy) __asm("llvm.amdgcn.raw.buffer.store.v4i32");
#define CP_SC01 17   // sc0|sc1: device-coherent, L1/L2-bypass (R11-proven)

static __device__ __forceinline__ i32x4 make_srd(const char* p) {
  i32x4 r;
  r.x = (int)(uint32_t)(uintptr_t)p;
  r.y = (int)(uint32_t)((uintptr_t)p >> 32);
  r.z = (int)0xFFFFFFFF;
  r.w = 0x00020000;
  return r;
}
static __device__ __forceinline__ uint4 bload(i32x4 srd, int voff) {
  return __builtin_bit_cast(uint4, llvm_amdgcn_raw_buffer_load_i32x4(srd, voff, 0, CP_SC01));
}
static __device__ __forceinline__ void bstore(i32x4 srd, int voff, uint4 v) {
  llvm_amdgcn_raw_buffer_store_i32x4(__builtin_bit_cast(i32x4, v), srd, voff, 0, CP_SC01);
}

static __device__ __forceinline__ uint16_t f2b(float f) {
  union { float f; uint32_t u; } v; v.f = f;
  uint32_t r = (v.u + 0x7FFFu + ((v.u >> 16) & 1u)) >> 16;  // RNE
  return (uint16_t)r;
}
static __device__ __forceinline__ uint4 cvt8(const float* s) {
  uint4 o;
  o.x = (uint32_t)f2b(s[0]) | ((uint32_t)f2b(s[1]) << 16);
  o.y = (uint32_t)f2b(s[2]) | ((uint32_t)f2b(s[3]) << 16);
  o.z = (uint32_t)f2b(s[4]) | ((uint32_t)f2b(s[5]) << 16);
  o.w = (uint32_t)f2b(s[6]) | ((uint32_t)f2b(s[7]) << 16);
  return o;
}
static __device__ __forceinline__ f32x4 mfma16(uint4 a, uint4 b, f32x4 c) {
  return __builtin_amdgcn_mfma_f32_16x16x32_bf16(
      __builtin_bit_cast(bf16x8, a), __builtin_bit_cast(bf16x8, b), c, 0, 0, 0);
}
static __device__ __forceinline__ float sigm(float x)  { return 1.0f / (1.0f + __expf(-x)); }
static __device__ __forceinline__ float tanhx(float x) { return 1.0f - 2.0f / (__expf(2.0f * x) + 1.0f); }
static __device__ __forceinline__ int imin2(int a, int b) { return a < b ? a : b; }

#define FLD(i) ((int)__hip_atomic_load(fl + (i), __ATOMIC_RELAXED, __HIP_MEMORY_SCOPE_AGENT))
#define CROW 65   // padded cpart row stride in uint4 units (bank-conflict fix, R13-confirmed)

// R16-proven: hard anti-hoist boundary after each poll.
static __device__ __forceinline__ void load_fence() {
  __builtin_amdgcn_fence(__ATOMIC_ACQUIRE, "workgroup");
  __builtin_amdgcn_sched_barrier(0);
  asm volatile("" ::: "memory");
}

// ---------------- pack kernels (identical to R4-R16) ----------------
__global__ void pack_w0(const float* __restrict__ wih, const float* __restrict__ whh,
                        char* __restrict__ ws) {
  uint32_t u = blockIdx.x * blockDim.x + threadIdx.x;   // 786432
  int lane = u & 63;
  uint32_t idx = u >> 6;            // (bw*4 + w)*48 + j
  int j = (int)(idx % 48u);
  uint32_t r2 = idx / 48u;
  int w = r2 & 3, bw = r2 >> 2;
  int c = (j & 3) * 16 + (lane & 15);
  int g_row = (c & 3) * 1024 + bw * 16 + (c >> 2);
  uint4 v;
  if (j < 16) {
    int k = w * 128 + (j >> 2) * 32 + (lane >> 4) * 8;
    v = cvt8(wih + (size_t)g_row * 512 + k);
  } else {
    int k = w * 256 + ((j - 16) >> 2) * 32 + (lane >> 4) * 8;
    v = cvt8(whh + (size_t)g_row * 1024 + k);
  }
  ((uint4*)(ws + OFF_WP0))[u] = v;
}
__global__ void pack_w1(const float* __restrict__ wih, const float* __restrict__ whh,
                        char* __restrict__ ws) {
  uint32_t u = blockIdx.x * blockDim.x + threadIdx.x;   // 1048576
  int lane = u & 63;
  int j = (u >> 6) & 31;
  int w = (u >> 11) & 3;
  int bw = u >> 13;
  int c = (j & 1) * 16 + (lane & 15);
  int g_row = (c & 3) * 1024 + bw * 8 + (c >> 2);
  int k = w * 512 + (j >> 1) * 32 + (lane >> 4) * 8;
  uint4 v;
  if (k < 1024) v = cvt8(wih + (size_t)g_row * 1024 + k);
  else          v = cvt8(whh + (size_t)g_row * 1024 + (k - 1024));
  ((uint4*)(ws + OFF_WP1))[u] = v;
}
__global__ void pack_x(const float* __restrict__ x, char* __restrict__ ws) {
  uint32_t u = blockIdx.x * blockDim.x + threadIdx.x;   // 1048576
  int lane = u & 63;
  int F = (u >> 6) & 63;
  int t = u >> 12;
  int r = (F & 3) * 16 + (lane & 15);
  int k = (F >> 2) * 32 + (lane >> 4) * 8;
  ((uint4*)(ws + OFF_XP))[u] = cvt8(x + (size_t)r * (TT * CIN) + (size_t)t * CIN + k);
}
__global__ void pack_bias(const float* __restrict__ bih0, const float* __restrict__ bhh0,
                          const float* __restrict__ bih1, const float* __restrict__ bhh1,
                          char* __restrict__ ws) {
  uint32_t v = blockIdx.x * blockDim.x + threadIdx.x;   // 8192
  if (v < 4096) ((float*)(ws + OFF_B0S))[v] = bih0[v] + bhh0[v];
  else          ((float*)(ws + OFF_B1S))[v - 4096] = bih1[v - 4096] + bhh1[v - 4096];
}

// ---------------- waits: exact producer sets (R18) ----------------
// k<->unit<->block maps: h0 units u -> L0 block u>>4 (flags 0..63);
// h1 units u -> L1 block u>>3 (flags 64..191).
static __device__ __forceinline__ void wait_L0(uint32_t* fl, int tgt) {
  const int lane = threadIdx.x & 63;
  for (;;) {
    int f0 = FLD(lane);
    int f1 = FLD(64 + lane);
    int f2 = FLD(128 + lane);
    int mn1 = imin2(f1, f2);
    if (__all(f0 >= tgt && mn1 >= tgt - 2)) break;   // RAW on h0 + loose L1 WAR
    __builtin_amdgcn_s_sleep(1);
  }
  load_fence();
}
// L1 waves 0,1: wave w reads h0 k in [w*512,(w+1)*512) -> L0 blocks w*32..w*32+31.
static __device__ __forceinline__ void wait_L1a(uint32_t* fl, int tgt, int wave) {
  const int lane = threadIdx.x & 63;
  const int si = wave * 32 + (lane & 31);
  for (;;) {
    int fs = FLD(si);
    if (__all(fs >= tgt)) break;
    __builtin_amdgcn_s_sleep(1);
  }
  load_fence();
}
// L1 waves 2,3: wave 2 reads h1 units 0..511 -> flags 64..127 (tight);
// wave 3 -> flags 128..191 (tight). Other half loose (h1 ring WAR, slack 2).
static __device__ __forceinline__ void wait_L1b(uint32_t* fl, int tgt, int wave) {
  const int lane = threadIdx.x & 63;
  const int tb = (wave == 2) ? 64 : 128;
  const int ob = (wave == 2) ? 128 : 64;
  for (;;) {
    int fs = FLD(tb + lane);
    int fo = FLD(ob + lane);
    if (__all(fs >= tgt && fo >= tgt - 2)) break;
    __builtin_amdgcn_s_sleep(1);
  }
  load_fence();
}

// ---------------- persistent LSTM ----------------
// blocks 0..63: layer0, 16 units each; blocks 64..191: layer1, 8 units each.
// phase p: L0 computes t=p (p<256), L1 computes t=p-1 (p>=1).
// h rings: write slot p&3, read slot (p+3)&3. Transport: buffer dwordx4 sc0 sc1 (R11).
__global__ __launch_bounds__(NTHR, 1) void lstm_persist(char* __restrict__ ws,
                                                        float* __restrict__ out) {
  __shared__ float cpart[64 * CROW * 4];         // padded: 64 rows x 65 uint4 (~65 KB)
  __shared__ __align__(16) uint16_t hreg[1024];  // 2 KB staged h tile
  const int tid = threadIdx.x, blk = blockIdx.x;
  const int wave = tid >> 6, lane = tid & 63;
  const bool isL1 = blk >= 64;
  const int bw = isL1 ? blk - 64 : blk;
  uint32_t* flags = (uint32_t*)(ws + OFF_FLG);

  const int eu  = isL1 ? (tid & 7)  : (tid & 15);
  const int erb = isL1 ? (tid >> 3) : (tid >> 4);
  const int ug  = isL1 ? (bw * 8 + eu) : (bw * 16 + eu);
  const float* bsrc = (const float*)(ws + (isL1 ? OFF_B1S : OFF_B0S));
  const float bs0 = bsrc[ug], bs1 = bsrc[1024 + ug], bs2 = bsrc[2048 + ug], bs3 = bsrc[3072 + ug];
  float cst[4] = {0.f, 0.f, 0.f, 0.f};

  // ---- persistent register-resident weights (full b[48] for L0) ----
  uint4 b[48];
  if (isL1) {
    const uint4* bp = (const uint4*)(ws + OFF_WP1) + ((size_t)(bw * 4 + wave) * 32) * 64 + lane;
    #pragma unroll
    for (int j = 0; j < 32; ++j) b[j] = bp[(size_t)j * 64];
  } else {
    const uint4* bp = (const uint4*)(ws + OFF_WP0) + ((size_t)(bw * 4 + wave) * 48) * 64 + lane;
    #pragma unroll
    for (int j = 0; j < 48; ++j) b[j] = bp[(size_t)j * 64];
  }

  for (int p = 0; p <= 256; ++p) {
    f32x4 acc[4][4];
    #pragma unroll
    for (int rf = 0; rf < 4; ++rf)
      #pragma unroll
      for (int cf = 0; cf < 4; ++cf)
        acc[rf][cf] = (f32x4){0.f, 0.f, 0.f, 0.f};

    if (!isL1) {
      if (p == 256) break;     // flag 256 already published after p=255
      // x-part first (plain cached loads): independent of flags, hides wait
      const uint4* xpl = (const uint4*)(ws + OFF_XP) + (size_t)p * 4096 + lane;
      #pragma unroll
      for (int jx = 0; jx < 4; ++jx) {
        const int kf = wave * 4 + jx;
        uint4 a0 = xpl[kf * 256], a1 = xpl[kf * 256 + 64],
              a2 = xpl[kf * 256 + 128], a3 = xpl[kf * 256 + 192];
        #pragma unroll
        for (int cf = 0; cf < 4; ++cf) {
          uint4 bb = b[jx * 4 + cf];
          acc[0][cf] = mfma16(a0, bb, acc[0][cf]);
          acc[1][cf] = mfma16(a1, bb, acc[1][cf]);
          acc[2][cf] = mfma16(a2, bb, acc[2][cf]);
          acc[3][cf] = mfma16(a3, bb, acc[3][cf]);
        }
      }
      if (p > 0) wait_L0(flags, p);
      const i32x4 srdh = make_srd(ws + OFF_H0 + (size_t)((p + 3) & 3) * SZ_HP);
      #pragma unroll
      for (int jh = 0; jh < 8; ++jh) {
        const int kf = wave * 8 + jh;
        const int base = (kf * 256 + lane) * 16;
        uint4 a0 = bload(srdh, base);
        uint4 a1 = bload(srdh, base + 64 * 16);
        uint4 a2 = bload(srdh, base + 128 * 16);
        uint4 a3 = bload(srdh, base + 192 * 16);
        #pragma unroll
        for (int cf = 0; cf < 4; ++cf) {
          uint4 bb = b[16 + jh * 4 + cf];
          acc[0][cf] = mfma16(a0, bb, acc[0][cf]);
          acc[1][cf] = mfma16(a1, bb, acc[1][cf]);
          acc[2][cf] = mfma16(a2, bb, acc[2][cf]);
          acc[3][cf] = mfma16(a3, bb, acc[3][cf]);
        }
      }
    } else {
      if (p == 0) {
        if (tid == 0)
          __hip_atomic_store(flags + blk, 1u, __ATOMIC_RELAXED, __HIP_MEMORY_SCOPE_AGENT);
        continue;
      }
      // exact-producer waits (R18)
      if (wave < 2) wait_L1a(flags, p, wave);
      else          wait_L1b(flags, p, wave);
      uint32_t boff = (uint32_t)(wave < 2 ? OFF_H0 : OFF_H1) + ((p + 3) & 3) * (uint32_t)SZ_HP;
      boff = __builtin_amdgcn_readfirstlane(boff);          // SRD must be scalar
      const i32x4 srdh = make_srd(ws + boff);
      const int kb = (wave & 1) * 16;
      #pragma unroll
      for (int jh = 0; jh < 16; ++jh) {
        const int kf = kb + jh;
        const int base = (kf * 256 + lane) * 16;
        uint4 a0 = bload(srdh, base);
        uint4 a1 = bload(srdh, base + 64 * 16);
        uint4 a2 = bload(srdh, base + 128 * 16);
        uint4 a3 = bload(srdh, base + 192 * 16);
        #pragma unroll
        for (int cf = 0; cf < 2; ++cf) {
          uint4 bb = b[jh * 2 + cf];
          acc[0][cf] = mfma16(a0, bb, acc[0][cf]);
          acc[1][cf] = mfma16(a1, bb, acc[1][cf]);
          acc[2][cf] = mfma16(a2, bb, acc[2][cf]);
          acc[3][cf] = mfma16(a3, bb, acc[3][cf]);
        }
      }
    }

    // ---- stash K-quarter partials (padded rows: stride CROW uint4) ----
    if (isL1) {
      #pragma unroll
      for (int rf = 0; rf < 4; ++rf)
        #pragma unroll
        for (int cf = 0; cf < 2; ++cf)
          *(f32x4*)&cpart[(((wave * 4 + rf) * 2 + cf) * CROW + lane) * 4] = acc[rf][cf];
    } else {
      #pragma unroll
      for (int rf = 0; rf < 4; ++rf)
        #pragma unroll
        for (int cf = 0; cf < 4; ++cf)
          *(f32x4*)&cpart[(((wave * 4 + rf) * 4 + cf) * CROW + lane) * 4] = acc[rf][cf];
    }
    __syncthreads();

    // ---- reduce + elementwise (c-state in f32 registers) ----
    if (isL1) {
      #pragma unroll
      for (int half = 0; half < 2; ++half) {
        const int r64 = erb + half * 32;
        const int rf = r64 >> 4, r16 = r64 & 15;
        const int reg = r16 & 3, lbase = 16 * (r16 >> 2);
        float gs[4];
        #pragma unroll
        for (int g = 0; g < 4; ++g) {
          const int c = eu * 4 + g;
          const int lc = (c & 15) + lbase;
          const int cf = c >> 4;
          float s = 0.f;
          #pragma unroll
          for (int w = 0; w < 4; ++w)
            s += cpart[(((w * 4 + rf) * 2 + cf) * CROW + lc) * 4 + reg];
          gs[g] = s;
        }
        const float iv = sigm(gs[0] + bs0), fv = sigm(gs[1] + bs1);
        const float gv = tanhx(gs[2] + bs2), ov = sigm(gs[3] + bs3);
        float cs = cst[half];
        cs = fv * cs + iv * gv;
        cst[half] = cs;
        const float hv = ov * tanhx(cs);
        hreg[r64 * 8 + eu] = f2b(hv);
        if (p == 256) out[(size_t)r64 * 1024 + ug] = hv;
      }
    } else {
      #pragma unroll
      for (int half = 0; half < 4; ++half) {
        const int r64 = erb + half * 16;      // erb < 16
        const int rf = half, r16 = erb;
        const int reg = r16 & 3, lbase = 16 * (r16 >> 2);
        float gs[4];
        #pragma unroll
        for (int g = 0; g < 4; ++g) {
          const int c = eu * 4 + g;           // [0,64)
          const int lc = (c & 15) + lbase;
          const int cf = c >> 4;
          float s = 0.f;
          #pragma unroll
          for (int w = 0; w < 4; ++w)
            s += cpart[(((w * 4 + rf) * 4 + cf) * CROW + lc) * 4 + reg];
          gs[g] = s;
        }
        const float iv = sigm(gs[0] + bs0), fv = sigm(gs[1] + bs1);
        const float gv = tanhx(gs[2] + bs2), ov = sigm(gs[3] + bs3);
        float cs = cst[half];
        cs = fv * cs + iv * gv;
        cst[half] = cs;
        const float hv = ov * tanhx(cs);
        hreg[r64 * 16 + eu] = f2b(hv);
      }
    }
    __syncthreads();

    // ---- publish h: buffer_store_dwordx4 sc0 sc1 -> barrier (drains vmcnt) -> flag ----
    if (p < 256) {
      if (isL1) {
        if (tid < 64) {
          uint4 v = ((const uint4*)hreg)[tid];          // row tid, units bw*8..+7
          const i32x4 srdw = make_srd(ws + OFF_H1 + (size_t)(p & 3) * SZ_HP);
          const int off = ((bw >> 2) * 4 + (tid >> 4)) * 1024 + (bw & 3) * 256 + (tid & 15) * 16;
          bstore(srdw, off, v);
        }
      } else {
        if (tid < 128) {
          uint4 v = ((const uint4*)hreg)[tid];          // row tid>>1, units (tid&1)*8..+8
          const i32x4 srdw = make_srd(ws + OFF_H0 + (size_t)(p & 3) * SZ_HP);
          const int off = ((bw >> 1) * 4 + (tid >> 5)) * 1024
                        + (2 * (bw & 1) + (tid & 1)) * 256 + ((tid >> 1) & 15) * 16;
          bstore(srdw, off, v);
        }
      }
      __syncthreads();   // each wave's s_waitcnt vmcnt(0) before s_barrier -> stores complete
      if (tid == 0)
        __hip_atomic_store(flags + blk, (uint32_t)(p + 1), __ATOMIC_RELAXED, __HIP_MEMORY_SCOPE_AGENT);
    }
  }
}

// ---------------- launcher ----------------
extern "C" void kernel_launch(void* const* d_in, const int* in_sizes, int n_in,
                              void* d_out, int out_size, void* d_ws, size_t ws_size,
                              hipStream_t stream) {
  const float* x    = (const float*)d_in[0];
  const float* Wih0 = (const float*)d_in[1];
  const float* Whh0 = (const float*)d_in[2];
  const float* bih0 = (const float*)d_in[3];
  const float* bhh0 = (const float*)d_in[4];
  const float* Wih1 = (const float*)d_in[5];
  const float* Whh1 = (const float*)d_in[6];
  const float* bih1 = (const float*)d_in[7];
  const float* bhh1 = (const float*)d_in[8];
  char* ws = (char*)d_ws;
  float* out = (float*)d_out;

  // zero h rings + flags (re-runs on every graph replay)
  hipMemsetAsync(ws + OFF_H0, 0, ZERO_SZ, stream);

  pack_w0  <<<3072, 256, 0, stream>>>(Wih0, Whh0, ws);
  pack_w1  <<<4096, 256, 0, stream>>>(Wih1, Whh1, ws);
  pack_x   <<<4096, 256, 0, stream>>>(x, ws);
  pack_bias<<<32,   256, 0, stream>>>(bih0, bhh0, bih1, bhh1, ws);

  void* args[] = {(void*)&ws, (void*)&out};
  hipError_t e = hipLaunchCooperativeKernel((const void*)lstm_persist, dim3(NBLK),
                                            dim3(NTHR), args, 0, stream);
  if (e != hipSuccess) {
    (void)hipGetLastError();   // clear sticky error; fall back to plain launch
    lstm_persist<<<dim3(NBLK), dim3(NTHR), 0, stream>>>(ws, out);
  }
}